// Round 10
// baseline (317.232 us; speedup 1.0000x reference)
//
#include <hip/hip_runtime.h>
#include <hip/hip_cooperative_groups.h>
#include <stdint.h>

// Match numpy's unfused mul/add rounding everywhere (no FMA contraction).
#pragma clang fp contract(off)

namespace cg = cooperative_groups;
typedef unsigned long long ull;

// Problem constants (B=16, H=W=64, A=9, stride 16, img 1024x1024)
#define NB 16
#define NA 9
#define HW 4096
#define NANCH (NA*HW)         // 36864
#define TOTAL (NB*NANCH)      // 589824
#define TOPN 2000
#define PADN 2048             // boxes/areas padded with sentinel boxes
#define SELPAD 3072           // candidate buffer per batch
#define OUTN 300
#define NWORDS 32             // ull words per mask row
#define GD 16                 // greedy prefetch depth
#define HBITS 13
#define HBINS (1 << HBITS)    // 8192 LDS bins (fallback k_batch)
#define HB2 14
#define HBINS2 (1 << HB2)     // 16384 global bins (coop path)
#define NBLK 256
#define NTHR 256
#define GSIZE (NBLK*NTHR)     // 65536

// exact: RN32(inter/u) > 0.7f  <=>  (double)inter >= MIDC*(double)u
// 0.7f = 0x1.666666p-1; next = 0x1.666668p-1; midpoint = 0x1.666667p-1 exactly.
// 25x24-bit product exact in double; tie rounds-to-even onto the upper neighbor.
#define MIDC 0x1.666667p-1

// 9 base anchors (x1,y1,x2,y2), computed exactly per the numpy generator
__constant__ float c_ax1[9] = {-3.5f,-15.f,-38.f,  0.f, -8.f,-24.f,  2.5f, -3.f,-14.f};
__constant__ float c_ay1[9] = { 2.f,  -4.f,-16.f,  0.f, -8.f,-24.f, -3.f,-14.f,-36.f};
__constant__ float c_ax2[9] = {18.5f, 30.f, 53.f, 15.f, 23.f, 39.f, 12.5f, 18.f, 29.f};
__constant__ float c_ay2[9] = {13.f,  19.f, 31.f, 15.f, 23.f, 39.f, 18.f,  29.f, 51.f};

__device__ __forceinline__ void decode_box(int a, int x, int y,
    float d0, float d1, float d2, float d3,
    float& x1, float& y1, float& x2, float& y2) {
  float ax1 = c_ax1[a] + 16.f * (float)x;
  float ay1 = c_ay1[a] + 16.f * (float)y;
  float ax2 = c_ax2[a] + 16.f * (float)x;
  float ay2 = c_ay2[a] + 16.f * (float)y;
  float aw  = ax2 - ax1 + 1.f;
  float ah  = ay2 - ay1 + 1.f;
  float acx = ax1 + 0.5f * aw;
  float acy = ay1 + 0.5f * ah;
  float cx = d0 * aw + acx;
  float cy = d1 * ah + acy;
  float pw = expf(d2) * aw;
  float ph = expf(d3) * ah;
  x1 = cx - 0.5f * pw;
  y1 = cy - 0.5f * ph;
  x2 = cx + 0.5f * pw;
  y2 = cy + 0.5f * ph;
  x1 = fminf(fmaxf(x1, 0.f), 1023.f);
  y1 = fminf(fmaxf(y1, 0.f), 1023.f);
  x2 = fminf(fmaxf(x2, 0.f), 1023.f);
  y2 = fminf(fmaxf(y2, 0.f), 1023.f);
}

__device__ __forceinline__ uint32_t f2ord(float f) {
  uint32_t u = __float_as_uint(f);
  return (u & 0x80000000u) ? ~u : (u | 0x80000000u);
}
__device__ __forceinline__ float ord2f(uint32_t u) {
  return (u & 0x80000000u) ? __uint_as_float(u ^ 0x80000000u) : __uint_as_float(~u);
}

// ====================== COOPERATIVE single-kernel path ======================
__global__ __launch_bounds__(NTHR) void k_all(
    const float* __restrict__ labels, const float* __restrict__ bbox,
    float* __restrict__ out, uint32_t* __restrict__ keys, ull* __restrict__ selKeys,
    float* __restrict__ selScore, float* __restrict__ areas, float4* __restrict__ boxes,
    ull* __restrict__ masks, uint32_t* __restrict__ hist,
    uint32_t* __restrict__ counters, uint32_t* __restrict__ tinfo) {
  cg::grid_group grid = cg::this_grid();
  const int tid = threadIdx.x, bid = blockIdx.x;
  const int gtid = bid * NTHR + tid;
  const int wave = tid >> 6, lane = tid & 63;

  __shared__ ull SH[2048];          // 16 KB, reused per phase
  __shared__ uint32_t sh_u32[8];

  // ---------- P0: zero hist + counters + tinfo ----------
#pragma unroll
  for (int k = 0; k < (NB * HBINS2) / GSIZE; ++k) hist[k * GSIZE + gtid] = 0u;
  if (gtid < NB) counters[gtid] = 0u;
  if (gtid >= NB && gtid < 2 * NB) tinfo[gtid - NB] = 0u;
  grid.sync();

  // ---------- P1: score keys (linear coalesced) + positive-only histogram ----------
  for (int t = gtid; t < TOTAL; t += GSIZE) {
    int pos = t & (HW - 1);
    int ba  = t >> 12;
    int a = ba % 9, b = ba / 9;
    float score = labels[((b * 18 + 2 * a + 1) << 12) + pos];
    const float* dp = bbox + ((b * 36 + 4 * a) << 12) + pos;
    float d0 = dp[0], d1 = dp[4096], d2 = dp[8192], d3 = dp[12288];
    int y = pos >> 6, x = pos & 63;
    float x1, y1, x2, y2;
    decode_box(a, x, y, d0, d1, d2, d3, x1, y1, x2, y2);
    bool keep = (x2 - x1 + 1.f >= 16.f) && (y2 - y1 + 1.f >= 16.f);
    float s = keep ? score : -INFINITY;
    uint32_t k = f2ord(s);
    keys[t] = k;
    if (k & 0x80000000u)
      atomicAdd(&hist[(b << HB2) + (k >> (32 - HB2))], 1u);
  }
  grid.sync();

  // ---------- P2: per-batch threshold bin (blocks 0..15) ----------
  if (bid < NB) {
    int b = bid;
    const uint32_t* h = hist + (b << HB2);
    const uint4* h4 = (const uint4*)(h + tid * 64);
    uint32_t s = 0;
#pragma unroll
    for (int i = 0; i < 16; ++i) { uint4 v = h4[i]; s += v.x + v.y + v.z + v.w; }
    uint32_t suf = s;
#pragma unroll
    for (int off = 1; off < 64; off <<= 1) {
      uint32_t v = __shfl_down(suf, off);
      if (lane + off < 64) suf += v;
    }
    if (lane == 0) sh_u32[wave] = suf;
    if (tid == 5) { sh_u32[4] = 0u; sh_u32[5] = 0u; }   // default
    __syncthreads();
    uint32_t wab = 0;
    for (int w2 = wave + 1; w2 < 4; ++w2) wab += sh_u32[w2];
    uint32_t ssum = suf + wab;          // sum of chunks >= tid
    uint32_t above = ssum - s;          // sum of chunks >  tid
    if (above < TOPN && ssum >= TOPN) { sh_u32[4] = (uint32_t)tid; sh_u32[5] = above; }
    __syncthreads();
    int c = (int)sh_u32[4];
    uint32_t accA = sh_u32[5];
    if (tid < 64) {
      uint32_t cb = h[c * 64 + tid];
      uint32_t s2 = cb;
#pragma unroll
      for (int off = 1; off < 64; off <<= 1) {
        uint32_t v = __shfl_down(s2, off);
        if (tid + off < 64) s2 += v;
      }
      uint32_t nxt = __shfl_down(s2, 1);
      uint32_t ab2 = accA + ((tid < 63) ? nxt : 0u);
      if (ab2 < TOPN && ab2 + cb >= TOPN) tinfo[b] = (uint32_t)(c * 64 + tid);
    }
  }
  grid.sync();

  // ---------- P3: compact keys >= threshold bin (288 units) ----------
  for (int u3 = bid; u3 < 288; u3 += NBLK) {
    int b = u3 / 18, chunk = u3 % 18;
    if (tid == 0) sh_u32[6] = 0u;
    __syncthreads();
    uint32_t T = tinfo[b];
    const uint32_t* kb = keys + b * NANCH + chunk * 2048;
#pragma unroll
    for (int k2 = 0; k2 < 8; ++k2) {
      int i = k2 * 256 + tid;
      uint32_t u = kb[i];
      if ((u >> (32 - HB2)) >= T) {
        uint32_t slot = atomicAdd(&sh_u32[6], 1u);            // LDS atomic
        int ilin = chunk * 2048 + i;                          // [a][pos] linear
        uint32_t canon = (uint32_t)((ilin & 4095) * 9 + (ilin >> 12)); // pos*9+a
        SH[slot] = (((ull)(~u)) << 32) | canon;
      }
    }
    __syncthreads();
    if (tid == 0) sh_u32[7] = atomicAdd(&counters[b], sh_u32[6]);
    __syncthreads();
    uint32_t base = sh_u32[7], n = sh_u32[6];
    for (uint32_t s2 = tid; s2 < n; s2 += NTHR) {
      uint32_t slot = base + s2;
      if (slot < SELPAD) selKeys[b * SELPAD + slot] = SH[s2];
    }
    __syncthreads();
  }
  grid.sync();

  // ---------- P4: rank-by-counting + decode + sentinel pad (208 units) ----------
  if (bid < 192) {
    int b = bid / 12;
    int i = (bid % 12) * 256 + tid;
    uint32_t n = counters[b]; if (n > SELPAD) n = SELPAD;
    const ull* sk = selKeys + b * SELPAD;
    ull ki = (i < (int)n) ? sk[i] : ~0ull;
    int rank = 0;
    for (uint32_t base = 0; base < n; base += 256) {
      uint32_t j = base + (uint32_t)tid;
      SH[tid] = (j < n) ? sk[j] : ~0ull;
      __syncthreads();
      int lim = (int)(n - base < 256u ? n - base : 256u);
      for (int t2 = 0; t2 < lim; ++t2) rank += (SH[t2] < ki) ? 1 : 0;
      __syncthreads();
    }
    if (i < (int)n && rank < TOPN) {
      uint32_t idx = (uint32_t)ki;
      selScore[b * TOPN + rank] = ord2f(~((uint32_t)(ki >> 32)));
      int pos = (int)idx / 9, a = (int)idx - 9 * pos;
      int y = pos >> 6, x = pos & 63;
      const float* dp = bbox + ((b * 36 + 4 * a) << 12) + pos;
      float d0 = dp[0], d1 = dp[4096], d2 = dp[8192], d3 = dp[12288];
      float x1, y1, x2, y2;
      decode_box(a, x, y, d0, d1, d2, d3, x1, y1, x2, y2);
      boxes[b * PADN + rank] = make_float4(x1, y1, x2, y2);
      areas[b * PADN + rank] = (x2 - x1 + 1.f) * (y2 - y1 + 1.f);
    }
  } else if (bid < 208) {
    int b = bid - 192;
    if (tid < PADN - TOPN) {
      boxes[b * PADN + TOPN + tid] = make_float4(-1e8f, -1e8f, -1e8f, -1e8f);
      areas[b * PADN + TOPN + tid] = 1.0f;
    }
  }
  grid.sync();

  // ---------- P5: IoU suppression masks (144 strips x 16 batches) ----------
  for (int u5 = bid; u5 < 144 * NB; u5 += NBLK) {
    int b = u5 / 144, g144 = u5 % 144;
    int g = 0, off = 0;
    while (off + ((8 - g) << 2) <= g144) { off += (8 - g) << 2; ++g; }
    int rem = g144 - off;
    int rb = (g << 2) + (rem & 3);       // row tile 0..31
    int s5 = g + (rem >> 2);             // strip 0..7 (4s+3 >= rb)
    int t = wave;
    int cb = 4 * s5 + t;
    float4* colB = (float4*)SH;          // SH[0..511]
    float*  colA = (float*)(SH + 512);   // SH[512..639]
    ull*    tw   = SH + 640;             // SH[640..895]
    int j = s5 * 256 + tid;
    float4 bj0 = boxes[b * PADN + j];
    bj0.z += 1.f; bj0.w += 1.f;          // fold the +1 (exact)
    colB[tid] = bj0;
    colA[tid] = areas[b * PADN + j];
    __syncthreads();
    int i = rb * 64 + lane;
    ull m = 0ull;
    if (cb >= rb) {
      float4 bi = boxes[b * PADN + i];
      float biz1 = bi.z + 1.f, biw1 = bi.w + 1.f;
      float areai = areas[b * PADN + i];
      const double MD = MIDC;
      if (cb > rb) {
#pragma unroll
        for (int jj = 0; jj < 64; ++jj) {
          float4 bj = colB[(t << 6) + jj];
          float iw = fminf(biz1, bj.z) - fmaxf(bi.x, bj.x); iw = fmaxf(0.f, iw);
          float ih = fminf(biw1, bj.w) - fmaxf(bi.y, bj.y); ih = fmaxf(0.f, ih);
          float inter = iw * ih;
          float uu = (areai + colA[(t << 6) + jj]) - inter;
          if ((double)inter >= MD * (double)uu) m |= (1ull << jj);
        }
      } else {
#pragma unroll
        for (int jj = 0; jj < 64; ++jj) {
          if (jj > lane) {
            float4 bj = colB[(t << 6) + jj];
            float iw = fminf(biz1, bj.z) - fmaxf(bi.x, bj.x); iw = fmaxf(0.f, iw);
            float ih = fminf(biw1, bj.w) - fmaxf(bi.y, bj.y); ih = fmaxf(0.f, ih);
            float inter = iw * ih;
            float uu = (areai + colA[(t << 6) + jj]) - inter;
            if ((double)inter >= MD * (double)uu) m |= (1ull << jj);
          }
        }
      }
    }
    tw[(t << 6) + lane] = m;
    __syncthreads();
    if (tid < 64) {
      int i2 = rb * 64 + tid;
      if (i2 < TOPN) {
        ull* dst = &masks[((size_t)(b * TOPN + i2)) * NWORDS + 4 * s5];
        ulonglong2 p0, p1;
        p0.x = tw[tid]; p0.y = tw[64 + tid];
        p1.x = tw[128 + tid]; p1.y = tw[192 + tid];
        ((ulonglong2*)dst)[0] = p0;
        ((ulonglong2*)dst)[1] = p1;
      }
    }
    __syncthreads();
  }
  grid.sync();

  // ---------- P6: greedy scan + output (blocks 0..15) ----------
  if (bid < NB) {
    int b = bid;
    const uint32_t* mrows = (const uint32_t*)(masks + (size_t)(b * TOPN) * NWORDS);
    int* kept = (int*)SH;
    if (wave == 0) {
      uint32_t m[GD];
#pragma unroll
      for (int ph = 0; ph < GD; ++ph) m[ph] = mrows[ph * 64 + lane];
      uint32_t supw = 0u;
      int cnt = 0;
      for (int base = 0; base < TOPN; base += GD) {
#pragma unroll
        for (int ph = 0; ph < GD; ++ph) {
          int i = base + ph;
          uint32_t sw = __shfl(supw, i >> 5);
          if (!((sw >> (i & 31)) & 1u)) {
            uint32_t mm = (lane >= (uint32_t)((i >> 6) << 1)) ? m[ph] : 0u;
            supw |= mm;
            if (lane == 0 && cnt < OUTN) kept[cnt] = i;
            cnt++;
          }
          int nx = i + GD; if (nx > TOPN - 1) nx = TOPN - 1;
          m[ph] = mrows[nx * 64 + lane];
        }
        if (cnt >= OUTN) break;
      }
      if (lane == 0) sh_u32[6] = (uint32_t)(cnt < OUTN ? cnt : OUTN);
    }
    __syncthreads();
    int c = (int)sh_u32[6];
    float4* ob = (float4*)out;
    for (int s2 = tid; s2 < OUTN; s2 += NTHR) {
      float4 bx = make_float4(0.f, 0.f, 0.f, 0.f);
      float sc = 0.f;
      if (s2 < c) {
        int i = kept[s2];
        bx = boxes[b * PADN + i];
        sc = selScore[b * TOPN + i];
      }
      ob[b * OUTN + s2] = bx;
      out[NB * OUTN * 4 + b * OUTN + s2] = sc;
    }
  }
}

// ====================== FALLBACK multi-kernel path (proven, round 9) ======================
__global__ void k_score(const float* __restrict__ labels, const float* __restrict__ bbox,
                        uint32_t* __restrict__ keys) {
  int t = blockIdx.x * 256 + threadIdx.x;
  if (t >= TOTAL) return;
  int pos = t & (HW - 1);
  int ba  = t >> 12;
  int a = ba % 9, b = ba / 9;
  float score = labels[((b * 18 + 2 * a + 1) << 12) + pos];
  const float* dp = bbox + ((b * 36 + 4 * a) << 12) + pos;
  float d0 = dp[0], d1 = dp[4096], d2 = dp[8192], d3 = dp[12288];
  int y = pos >> 6, x = pos & 63;
  float x1, y1, x2, y2;
  decode_box(a, x, y, d0, d1, d2, d3, x1, y1, x2, y2);
  bool keep = (x2 - x1 + 1.f >= 16.f) && (y2 - y1 + 1.f >= 16.f);
  float s = keep ? score : -INFINITY;
  keys[t] = f2ord(s);
}

__global__ __launch_bounds__(1024) void k_batch(const uint32_t* __restrict__ keys,
                                                ull* __restrict__ selKeys,
                                                uint32_t* __restrict__ counters) {
  int b = blockIdx.x, tid = threadIdx.x;
  int wave = tid >> 6, lane = tid & 63;
  __shared__ uint32_t hist[HBINS];
  __shared__ uint32_t wtot[16];
  __shared__ uint32_t sh_T, sh_cnt;
  const uint32_t* kb = keys + b * NANCH;
#pragma unroll
  for (int k = 0; k < HBINS / 1024; ++k) hist[k * 1024 + tid] = 0u;
  if (tid == 0) { sh_T = 0u; sh_cnt = 0u; }
  __syncthreads();
  for (int i = tid; i < NANCH; i += 1024) {
    uint32_t u = kb[i];
    if (u & 0x80000000u) atomicAdd(&hist[u >> (32 - HBITS)], 1u);
  }
  __syncthreads();
  uint32_t c[8], suf[8];
#pragma unroll
  for (int k = 0; k < 8; ++k) c[k] = hist[tid * 8 + k];
  suf[7] = c[7];
#pragma unroll
  for (int k = 6; k >= 0; --k) suf[k] = c[k] + suf[k + 1];
  uint32_t total = suf[0];
  uint32_t wsuf = total;
#pragma unroll
  for (int off = 1; off < 64; off <<= 1) {
    uint32_t v = __shfl_down(wsuf, off);
    if (lane + off < 64) wsuf += v;
  }
  if (lane == 0) wtot[wave] = wsuf;
  __syncthreads();
  uint32_t wab = 0;
  for (int w = wave + 1; w < 16; ++w) wab += wtot[w];
  uint32_t ssum = wsuf + wab;
  uint32_t above_t = ssum - total;
  if (above_t < TOPN && ssum >= TOPN) {
    uint32_t T = (uint32_t)(tid * 8);
#pragma unroll
    for (int k = 7; k >= 0; --k) {
      uint32_t ab = above_t + ((k < 7) ? suf[k + 1] : 0u);
      if (ab < TOPN && ab + c[k] >= TOPN) T = (uint32_t)(tid * 8 + k);
    }
    sh_T = T;
  }
  __syncthreads();
  uint32_t T = sh_T;
  for (int i = tid; i < NANCH; i += 1024) {
    uint32_t u = kb[i];
    if ((u >> (32 - HBITS)) >= T) {
      uint32_t slot = atomicAdd(&sh_cnt, 1u);
      if (slot < SELPAD) {
        uint32_t canon = (uint32_t)((i & 4095) * 9 + (i >> 12));
        selKeys[b * SELPAD + slot] = (((ull)(~u)) << 32) | canon;
      }
    }
  }
  __syncthreads();
  if (tid == 0) counters[b] = (sh_cnt < SELPAD) ? sh_cnt : SELPAD;
}

__global__ __launch_bounds__(256) void k_rank(const ull* __restrict__ selKeys,
                        const uint32_t* __restrict__ counters, const float* __restrict__ bbox,
                        float4* __restrict__ boxes, float* __restrict__ areas,
                        float* __restrict__ selScore) {
  int b = blockIdx.y;
  int i = blockIdx.x * 256 + threadIdx.x;
  int tid = threadIdx.x;
  uint32_t n = counters[b];
  const ull* sk = selKeys + b * SELPAD;
  ull ki = (i < (int)n) ? sk[i] : ~0ull;
  int rank = 0;
  __shared__ ull chunk[256];
  for (uint32_t base = 0; base < n; base += 256) {
    uint32_t j = base + (uint32_t)tid;
    chunk[tid] = (j < n) ? sk[j] : ~0ull;
    __syncthreads();
    int lim = (int)(n - base < 256u ? n - base : 256u);
    for (int t2 = 0; t2 < lim; ++t2) rank += (chunk[t2] < ki) ? 1 : 0;
    __syncthreads();
  }
  if (i < (int)n && rank < TOPN) {
    uint32_t idx = (uint32_t)ki;
    selScore[b * TOPN + rank] = ord2f(~((uint32_t)(ki >> 32)));
    int pos = (int)idx / 9, a = (int)idx - 9 * pos;
    int y = pos >> 6, x = pos & 63;
    const float* dp = bbox + ((b * 36 + 4 * a) << 12) + pos;
    float d0 = dp[0], d1 = dp[4096], d2 = dp[8192], d3 = dp[12288];
    float x1, y1, x2, y2;
    decode_box(a, x, y, d0, d1, d2, d3, x1, y1, x2, y2);
    boxes[b * PADN + rank] = make_float4(x1, y1, x2, y2);
    areas[b * PADN + rank] = (x2 - x1 + 1.f) * (y2 - y1 + 1.f);
  }
  if (blockIdx.x == 0 && tid < PADN - TOPN) {
    boxes[b * PADN + TOPN + tid] = make_float4(-1e8f, -1e8f, -1e8f, -1e8f);
    areas[b * PADN + TOPN + tid] = 1.0f;
  }
}

__global__ __launch_bounds__(256) void k_iou(const float4* __restrict__ boxes,
                                             const float* __restrict__ areas,
                                             ull* __restrict__ masks) {
  int g144 = blockIdx.x, b = blockIdx.y;
  int g = 0, off = 0;
  while (off + ((8 - g) << 2) <= g144) { off += (8 - g) << 2; ++g; }
  int rem = g144 - off;
  int rb = (g << 2) + (rem & 3);
  int s  = g + (rem >> 2);
  int tid = threadIdx.x;
  int t = tid >> 6, lane = tid & 63;
  int cb = 4 * s + t;
  __shared__ float4 colB[256];
  __shared__ float  colA[256];
  __shared__ ull    tw[4][64];
  int j = s * 256 + tid;
  float4 bj0 = boxes[b * PADN + j];
  bj0.z += 1.f; bj0.w += 1.f;
  colB[tid] = bj0;
  colA[tid] = areas[b * PADN + j];
  __syncthreads();
  int i = rb * 64 + lane;
  ull m = 0ull;
  if (cb >= rb) {
    float4 bi = boxes[b * PADN + i];
    float biz1 = bi.z + 1.f, biw1 = bi.w + 1.f;
    float areai = areas[b * PADN + i];
    const double MD = MIDC;
    if (cb > rb) {
#pragma unroll
      for (int jj = 0; jj < 64; ++jj) {
        float4 bj = colB[(t << 6) + jj];
        float iw = fminf(biz1, bj.z) - fmaxf(bi.x, bj.x); iw = fmaxf(0.f, iw);
        float ih = fminf(biw1, bj.w) - fmaxf(bi.y, bj.y); ih = fmaxf(0.f, ih);
        float inter = iw * ih;
        float uu = (areai + colA[(t << 6) + jj]) - inter;
        if ((double)inter >= MD * (double)uu) m |= (1ull << jj);
      }
    } else {
#pragma unroll
      for (int jj = 0; jj < 64; ++jj) {
        if (jj > lane) {
          float4 bj = colB[(t << 6) + jj];
          float iw = fminf(biz1, bj.z) - fmaxf(bi.x, bj.x); iw = fmaxf(0.f, iw);
          float ih = fminf(biw1, bj.w) - fmaxf(bi.y, bj.y); ih = fmaxf(0.f, ih);
          float inter = iw * ih;
          float uu = (areai + colA[(t << 6) + jj]) - inter;
          if ((double)inter >= MD * (double)uu) m |= (1ull << jj);
        }
      }
    }
  }
  tw[t][lane] = m;
  __syncthreads();
  if (tid < 64) {
    int i2 = rb * 64 + tid;
    if (i2 < TOPN) {
      ull* dst = &masks[((size_t)(b * TOPN + i2)) * NWORDS + 4 * s];
      ulonglong2 p0, p1;
      p0.x = tw[0][tid]; p0.y = tw[1][tid];
      p1.x = tw[2][tid]; p1.y = tw[3][tid];
      ((ulonglong2*)dst)[0] = p0;
      ((ulonglong2*)dst)[1] = p1;
    }
  }
}

__global__ void k_greedy(const ull* __restrict__ masks,
                         const float4* __restrict__ boxes, const float* __restrict__ scores,
                         float* __restrict__ out) {
  int b = blockIdx.x, lane = threadIdx.x;
  const uint32_t* mrows = (const uint32_t*)(masks + (size_t)(b * TOPN) * NWORDS);
  uint32_t m[GD];
#pragma unroll
  for (int ph = 0; ph < GD; ++ph) m[ph] = mrows[ph * 64 + lane];
  uint32_t supw = 0u;
  __shared__ int kept[OUTN];
  int cnt = 0;
  for (int base = 0; base < TOPN; base += GD) {
#pragma unroll
    for (int ph = 0; ph < GD; ++ph) {
      int i = base + ph;
      uint32_t sw = __shfl(supw, i >> 5);
      if (!((sw >> (i & 31)) & 1u)) {
        uint32_t mm = (lane >= (uint32_t)((i >> 6) << 1)) ? m[ph] : 0u;
        supw |= mm;
        if (lane == 0 && cnt < OUTN) kept[cnt] = i;
        cnt++;
      }
      int nx = i + GD; if (nx > TOPN - 1) nx = TOPN - 1;
      m[ph] = mrows[nx * 64 + lane];
    }
    if (cnt >= OUTN) break;
  }
  __syncthreads();
  int c = cnt < OUTN ? cnt : OUTN;
  float4* ob = (float4*)out;
  for (int s2 = lane; s2 < OUTN; s2 += 64) {
    float4 bx = make_float4(0.f, 0.f, 0.f, 0.f);
    float sc = 0.f;
    if (s2 < c) {
      int i = kept[s2];
      bx = boxes[b * PADN + i];
      sc = scores[b * TOPN + i];
    }
    ob[b * OUTN + s2] = bx;
    out[NB * OUTN * 4 + b * OUTN + s2] = sc;
  }
}

extern "C" void kernel_launch(void* const* d_in, const int* in_sizes, int n_in,
                              void* d_out, int out_size, void* d_ws, size_t ws_size,
                              hipStream_t stream) {
  const float* labels = (const float*)d_in[0];  // (16, 18, 64, 64)
  const float* bbox   = (const float*)d_in[1];  // (16, 36, 64, 64)
  char* ws = (char*)d_ws;
  // workspace layout (bytes):
  uint32_t* keys    = (uint32_t*)(ws + 0);         // 589824*4     = 2,359,296
  ull* selKeys      = (ull*)(ws + 2359296);        // 16*3072*8    =   393,216
  float* selScore   = (float*)(ws + 2752512);      // 16*2000*4    =   128,000
  float* areas      = (float*)(ws + 2880512);      // 16*2048*4    =   131,072
  float4* boxes     = (float4*)(ws + 3011584);     // 16*2048*16   =   524,288
  ull* masks        = (ull*)(ws + 3535872);        // 16*2000*32*8 = 8,192,000
  uint32_t* counters= (uint32_t*)(ws + 11727872);  // 64
  uint32_t* tinfo   = (uint32_t*)(ws + 11727936);  // 64
  uint32_t* hist    = (uint32_t*)(ws + 11728128);  // 16*16384*4   = 1,048,576 (coop only)
  float* out = (float*)d_out;

  void* kargs[] = { &labels, &bbox, &out, &keys, &selKeys, &selScore, &areas,
                    &boxes, &masks, &hist, &counters, &tinfo };
  hipError_t e = hipLaunchCooperativeKernel((void*)k_all, dim3(NBLK), dim3(NTHR),
                                            kargs, 0, stream);
  if (e != hipSuccess) {
    (void)hipGetLastError();   // clear sticky error; fall back to proven path
    hipLaunchKernelGGL(k_score,  dim3((TOTAL + 255) / 256), dim3(256), 0, stream, labels, bbox, keys);
    hipLaunchKernelGGL(k_batch,  dim3(NB), dim3(1024), 0, stream, keys, selKeys, counters);
    hipLaunchKernelGGL(k_rank,   dim3(SELPAD / 256, NB), dim3(256), 0, stream, selKeys, counters, bbox, boxes, areas, selScore);
    hipLaunchKernelGGL(k_iou,    dim3(144, NB), dim3(256), 0, stream, boxes, areas, masks);
    hipLaunchKernelGGL(k_greedy, dim3(NB), dim3(64), 0, stream, masks, boxes, selScore, out);
  }
}

// Round 11
// 230.303 us; speedup vs baseline: 1.3775x; 1.3775x over previous
//
#include <hip/hip_runtime.h>
#include <stdint.h>

// Match numpy's unfused mul/add rounding everywhere (no FMA contraction).
#pragma clang fp contract(off)

typedef unsigned long long ull;

// Problem constants (B=16, H=W=64, A=9, stride 16, img 1024x1024)
#define NB 16
#define NA 9
#define HW 4096
#define NANCH (NA*HW)         // 36864
#define TOTAL (NB*NANCH)      // 589824
#define TOPN 2000
#define PADN 2048             // box/area buffer stride
#define SELPAD 3072           // candidate buffer per batch
#define OUTN 300
#define HBITS 13
#define HBINS (1 << HBITS)    // 8192 LDS histogram bins

// exact: RN32(inter/u) > 0.7f  <=>  (double)inter >= MIDC*(double)u
// 0.7f = 0x1.666666p-1; next = 0x1.666668p-1; midpoint = 0x1.666667p-1 exactly
// representable in double. inter can never equal MIDC*uu exactly (25-bit odd
// mantissa x 24-bit float product needs >24 significant bits), so >= == >.
// Tie-to-even at the midpoint rounds DOWN to 0.7f (even mantissa), matching.
#define MIDC 0x1.666667p-1

// 9 base anchors (x1,y1,x2,y2), computed exactly per the numpy generator
__constant__ float c_ax1[9] = {-3.5f,-15.f,-38.f,  0.f, -8.f,-24.f,  2.5f, -3.f,-14.f};
__constant__ float c_ay1[9] = { 2.f,  -4.f,-16.f,  0.f, -8.f,-24.f, -3.f,-14.f,-36.f};
__constant__ float c_ax2[9] = {18.5f, 30.f, 53.f, 15.f, 23.f, 39.f, 12.5f, 18.f, 29.f};
__constant__ float c_ay2[9] = {13.f,  19.f, 31.f, 15.f, 23.f, 39.f, 18.f,  29.f, 51.f};

__device__ __forceinline__ void decode_box(int a, int x, int y,
    float d0, float d1, float d2, float d3,
    float& x1, float& y1, float& x2, float& y2) {
  float ax1 = c_ax1[a] + 16.f * (float)x;
  float ay1 = c_ay1[a] + 16.f * (float)y;
  float ax2 = c_ax2[a] + 16.f * (float)x;
  float ay2 = c_ay2[a] + 16.f * (float)y;
  float aw  = ax2 - ax1 + 1.f;
  float ah  = ay2 - ay1 + 1.f;
  float acx = ax1 + 0.5f * aw;
  float acy = ay1 + 0.5f * ah;
  float cx = d0 * aw + acx;
  float cy = d1 * ah + acy;
  float pw = expf(d2) * aw;
  float ph = expf(d3) * ah;
  x1 = cx - 0.5f * pw;
  y1 = cy - 0.5f * ph;
  x2 = cx + 0.5f * pw;
  y2 = cy + 0.5f * ph;
  x1 = fminf(fmaxf(x1, 0.f), 1023.f);
  y1 = fminf(fmaxf(y1, 0.f), 1023.f);
  x2 = fminf(fmaxf(x2, 0.f), 1023.f);
  y2 = fminf(fmaxf(y2, 0.f), 1023.f);
}

__device__ __forceinline__ uint32_t f2ord(float f) {
  uint32_t u = __float_as_uint(f);
  return (u & 0x80000000u) ? ~u : (u | 0x80000000u);
}
__device__ __forceinline__ float ord2f(uint32_t u) {
  return (u & 0x80000000u) ? __uint_as_float(u ^ 0x80000000u) : __uint_as_float(~u);
}

// Kernel 1: masked ordered score keys, coalesced linear write keys[t]
// (t = ((b*9+a)<<12)|pos). Canonical tie-break index remap happens in k_batch.
__global__ void k_score(const float* __restrict__ labels, const float* __restrict__ bbox,
                        uint32_t* __restrict__ keys) {
  int t = blockIdx.x * 256 + threadIdx.x;
  if (t >= TOTAL) return;
  int pos = t & (HW - 1);
  int ba  = t >> 12;
  int a = ba % 9, b = ba / 9;
  float score = labels[((b * 18 + 2 * a + 1) << 12) + pos];
  const float* dp = bbox + ((b * 36 + 4 * a) << 12) + pos;
  float d0 = dp[0], d1 = dp[4096], d2 = dp[8192], d3 = dp[12288];
  int y = pos >> 6, x = pos & 63;
  float x1, y1, x2, y2;
  decode_box(a, x, y, d0, d1, d2, d3, x1, y1, x2, y2);
  bool keep = (x2 - x1 + 1.f >= 16.f) && (y2 - y1 + 1.f >= 16.f);
  float s = keep ? score : -INFINITY;
  keys[t] = f2ord(s);
}

// Kernel 2: per-batch LDS histogram (positive keys only) + suffix scan for the
// top-2000 threshold bin + compaction of all keys >= bin. 16 blocks x 1024.
__global__ __launch_bounds__(1024) void k_batch(const uint32_t* __restrict__ keys,
                                                ull* __restrict__ selKeys,
                                                uint32_t* __restrict__ counters) {
  int b = blockIdx.x, tid = threadIdx.x;
  int wave = tid >> 6, lane = tid & 63;
  __shared__ uint32_t hist[HBINS];         // 32 KB
  __shared__ uint32_t wtot[16];
  __shared__ uint32_t sh_T, sh_cnt;
  const uint32_t* kb = keys + b * NANCH;
#pragma unroll
  for (int k = 0; k < HBINS / 1024; ++k) hist[k * 1024 + tid] = 0u;
  if (tid == 0) { sh_T = 0u; sh_cnt = 0u; }
  __syncthreads();
  for (int i = tid; i < NANCH; i += 1024) {
    uint32_t u = kb[i];
    if (u & 0x80000000u) atomicAdd(&hist[u >> (32 - HBITS)], 1u);
  }
  __syncthreads();
  uint32_t c[8], suf[8];
#pragma unroll
  for (int k = 0; k < 8; ++k) c[k] = hist[tid * 8 + k];
  suf[7] = c[7];
#pragma unroll
  for (int k = 6; k >= 0; --k) suf[k] = c[k] + suf[k + 1];
  uint32_t total = suf[0];
  uint32_t wsuf = total;
#pragma unroll
  for (int off = 1; off < 64; off <<= 1) {
    uint32_t v = __shfl_down(wsuf, off);
    if (lane + off < 64) wsuf += v;
  }
  if (lane == 0) wtot[wave] = wsuf;
  __syncthreads();
  uint32_t wab = 0;
  for (int w = wave + 1; w < 16; ++w) wab += wtot[w];
  uint32_t ssum = wsuf + wab;          // keys in bins >= 8*tid
  uint32_t above_t = ssum - total;     // keys in bins >= 8*(tid+1)
  if (above_t < TOPN && ssum >= TOPN) {
    uint32_t T = (uint32_t)(tid * 8);
#pragma unroll
    for (int k = 7; k >= 0; --k) {
      uint32_t ab = above_t + ((k < 7) ? suf[k + 1] : 0u);
      if (ab < TOPN && ab + c[k] >= TOPN) T = (uint32_t)(tid * 8 + k);
    }
    sh_T = T;
  }
  __syncthreads();
  uint32_t T = sh_T;
  for (int i = tid; i < NANCH; i += 1024) {
    uint32_t u = kb[i];
    if ((u >> (32 - HBITS)) >= T) {
      uint32_t slot = atomicAdd(&sh_cnt, 1u);
      if (slot < SELPAD) {
        uint32_t canon = (uint32_t)((i & 4095) * 9 + (i >> 12));  // pos*9 + a
        selKeys[b * SELPAD + slot] = (((ull)(~u)) << 32) | canon;
      }
    }
  }
  __syncthreads();
  if (tid == 0) counters[b] = (sh_cnt < SELPAD) ? sh_cnt : SELPAD;
}

// Kernel 3: rank-by-counting (keys unique => rank == exact (score desc, idx asc)
// position) + decode + scatter of box/area/score to rank.
__global__ __launch_bounds__(256) void k_rank(const ull* __restrict__ selKeys,
                        const uint32_t* __restrict__ counters, const float* __restrict__ bbox,
                        float4* __restrict__ boxes, float* __restrict__ areas,
                        float* __restrict__ selScore) {
  int b = blockIdx.y;
  int i = blockIdx.x * 256 + threadIdx.x;
  int tid = threadIdx.x;
  uint32_t n = counters[b];
  const ull* sk = selKeys + b * SELPAD;
  ull ki = (i < (int)n) ? sk[i] : ~0ull;
  int rank = 0;
  __shared__ ull chunk[256];
  for (uint32_t base = 0; base < n; base += 256) {
    uint32_t j = base + (uint32_t)tid;
    chunk[tid] = (j < n) ? sk[j] : ~0ull;
    __syncthreads();
    int lim = (int)(n - base < 256u ? n - base : 256u);
    for (int t2 = 0; t2 < lim; ++t2) rank += (chunk[t2] < ki) ? 1 : 0;
    __syncthreads();
  }
  if (i < (int)n && rank < TOPN) {
    uint32_t idx = (uint32_t)ki;
    selScore[b * TOPN + rank] = ord2f(~((uint32_t)(ki >> 32)));
    int pos = (int)idx / 9, a = (int)idx - 9 * pos;
    int y = pos >> 6, x = pos & 63;
    const float* dp = bbox + ((b * 36 + 4 * a) << 12) + pos;
    float d0 = dp[0], d1 = dp[4096], d2 = dp[8192], d3 = dp[12288];
    float x1, y1, x2, y2;
    decode_box(a, x, y, d0, d1, d2, d3, x1, y1, x2, y2);
    boxes[b * PADN + rank] = make_float4(x1, y1, x2, y2);
    areas[b * PADN + rank] = (x2 - x1 + 1.f) * (y2 - y1 + 1.f);
  }
}

// Kernel 4: direct greedy NMS against the KEPT list (suppression in greedy NMS
// comes only from kept boxes). ~310 candidates visited x <=5 lane-chunks of
// kept tests instead of the 34M-pair mask matrix. Exact: same rank order, same
// IoU arithmetic ((min-max)+1 rounding order per reference), exact threshold
// test, exact first-300 early exit. One block per batch.
__global__ __launch_bounds__(256) void k_nms(const float4* __restrict__ boxes,
                                             const float* __restrict__ areas,
                                             const float* __restrict__ selScore,
                                             float* __restrict__ out) {
  int b = blockIdx.x, tid = threadIdx.x;
  __shared__ float cx1[TOPN], cy1[TOPN], cx2[TOPN], cy2[TOPN], car[TOPN]; // 40 KB
  __shared__ float kx1[OUTN], ky1[OUTN], kx2[OUTN], ky2[OUTN], kar[OUTN]; // 6 KB
  __shared__ int   kidx[OUTN];
  __shared__ int   sh_cnt;
  // stage candidates SoA (coalesced global float4 reads)
  for (int i = tid; i < TOPN; i += 256) {
    float4 v = boxes[b * PADN + i];
    cx1[i] = v.x; cy1[i] = v.y; cx2[i] = v.z; cy2[i] = v.w;
    car[i] = areas[b * PADN + i];
  }
  __syncthreads();
  if (tid < 64) {
    int lane = tid;
    int cnt = 0;
    const double MD = MIDC;
    for (int i = 0; i < TOPN; ++i) {
      float ix1 = cx1[i], iy1 = cy1[i], ix2 = cx2[i], iy2 = cy2[i], ia = car[i];
      bool sup = false;
      for (int c = 0; c < cnt; c += 64) {
        int k = c + lane;
        if (k < cnt) {
          float iw = fminf(ix2, kx2[k]) - fmaxf(ix1, kx1[k]) + 1.f; iw = fmaxf(iw, 0.f);
          float ih = fminf(iy2, ky2[k]) - fmaxf(iy1, ky1[k]) + 1.f; ih = fmaxf(ih, 0.f);
          float inter = iw * ih;
          float uu = (ia + kar[k]) - inter;
          sup = sup || ((double)inter >= MD * (double)uu);
        }
      }
      if (!__any(sup)) {
        if (lane == 0) {
          kx1[cnt] = ix1; ky1[cnt] = iy1; kx2[cnt] = ix2; ky2[cnt] = iy2;
          kar[cnt] = ia; kidx[cnt] = i;
        }
        cnt++;
        if (cnt >= OUTN) break;
      }
    }
    if (lane == 0) sh_cnt = cnt;
  }
  __syncthreads();
  int c = sh_cnt;
  float4* ob = (float4*)out;
  for (int s2 = tid; s2 < OUTN; s2 += 256) {
    float4 bx = make_float4(0.f, 0.f, 0.f, 0.f);
    float sc = 0.f;
    if (s2 < c) {
      bx = make_float4(kx1[s2], ky1[s2], kx2[s2], ky2[s2]);
      sc = selScore[b * TOPN + kidx[s2]];
    }
    ob[b * OUTN + s2] = bx;
    out[NB * OUTN * 4 + b * OUTN + s2] = sc;
  }
}

extern "C" void kernel_launch(void* const* d_in, const int* in_sizes, int n_in,
                              void* d_out, int out_size, void* d_ws, size_t ws_size,
                              hipStream_t stream) {
  const float* labels = (const float*)d_in[0];  // (16, 18, 64, 64)
  const float* bbox   = (const float*)d_in[1];  // (16, 36, 64, 64)
  char* ws = (char*)d_ws;
  // workspace layout (bytes):
  uint32_t* keys    = (uint32_t*)(ws + 0);         // 589824*4   = 2,359,296
  ull* selKeys      = (ull*)(ws + 2359296);        // 16*3072*8  =   393,216
  float* selScore   = (float*)(ws + 2752512);      // 16*2000*4  =   128,000
  float* areas      = (float*)(ws + 2880512);      // 16*2048*4  =   131,072
  float4* boxes     = (float4*)(ws + 3011584);     // 16*2048*16 =   524,288
  uint32_t* counters= (uint32_t*)(ws + 3535872);   // 64
  float* out = (float*)d_out;

  hipLaunchKernelGGL(k_score, dim3((TOTAL + 255) / 256), dim3(256), 0, stream, labels, bbox, keys);
  hipLaunchKernelGGL(k_batch, dim3(NB), dim3(1024), 0, stream, keys, selKeys, counters);
  hipLaunchKernelGGL(k_rank,  dim3(SELPAD / 256, NB), dim3(256), 0, stream, selKeys, counters, bbox, boxes, areas, selScore);
  hipLaunchKernelGGL(k_nms,   dim3(NB), dim3(256), 0, stream, boxes, areas, selScore, out);
}

// Round 12
// 158.591 us; speedup vs baseline: 2.0003x; 1.4522x over previous
//
#include <hip/hip_runtime.h>
#include <stdint.h>

// Match numpy's unfused mul/add rounding everywhere (no FMA contraction).
#pragma clang fp contract(off)

typedef unsigned long long ull;

// Problem constants (B=16, H=W=64, A=9, stride 16, img 1024x1024)
#define NB 16
#define NA 9
#define HW 4096
#define NANCH (NA*HW)         // 36864
#define TOTAL (NB*NANCH)      // 589824
#define TOPN 2000
#define PADN 2048             // box/area buffer stride
#define SELPAD 3072           // candidate buffer per batch
#define OUTN 300
#define HBITS 13
#define HBINS (1 << HBITS)    // 8192 LDS histogram bins
#define MNMS 512              // mask-matrix extent (scan provably ends ~310)
#define MW 16                 // u32 words per mask row (512 bits)
#define MPITCH 17             // padded pitch (bank-conflict-free)
#define GDN 8                 // scan prefetch depth

// exact: RN32(inter/u) > 0.7f  <=>  (double)inter >= MIDC*(double)u
// 0.7f = 0x1.666666p-1; next = 0x1.666668p-1; midpoint = 0x1.666667p-1 exactly
// representable in double; 25x24-bit product exact; tie-to-even rounds to the
// even (0.7f) side, so '>' at the midpoint is false — '>=' reproduces it.
// (HW-verified: absmax 0 in rounds 9-11.)
#define MIDC 0x1.666667p-1

// 9 base anchors (x1,y1,x2,y2), computed exactly per the numpy generator
__constant__ float c_ax1[9] = {-3.5f,-15.f,-38.f,  0.f, -8.f,-24.f,  2.5f, -3.f,-14.f};
__constant__ float c_ay1[9] = { 2.f,  -4.f,-16.f,  0.f, -8.f,-24.f, -3.f,-14.f,-36.f};
__constant__ float c_ax2[9] = {18.5f, 30.f, 53.f, 15.f, 23.f, 39.f, 12.5f, 18.f, 29.f};
__constant__ float c_ay2[9] = {13.f,  19.f, 31.f, 15.f, 23.f, 39.f, 18.f,  29.f, 51.f};

__device__ __forceinline__ void decode_box(int a, int x, int y,
    float d0, float d1, float d2, float d3,
    float& x1, float& y1, float& x2, float& y2) {
  float ax1 = c_ax1[a] + 16.f * (float)x;
  float ay1 = c_ay1[a] + 16.f * (float)y;
  float ax2 = c_ax2[a] + 16.f * (float)x;
  float ay2 = c_ay2[a] + 16.f * (float)y;
  float aw  = ax2 - ax1 + 1.f;
  float ah  = ay2 - ay1 + 1.f;
  float acx = ax1 + 0.5f * aw;
  float acy = ay1 + 0.5f * ah;
  float cx = d0 * aw + acx;
  float cy = d1 * ah + acy;
  float pw = expf(d2) * aw;
  float ph = expf(d3) * ah;
  x1 = cx - 0.5f * pw;
  y1 = cy - 0.5f * ph;
  x2 = cx + 0.5f * pw;
  y2 = cy + 0.5f * ph;
  x1 = fminf(fmaxf(x1, 0.f), 1023.f);
  y1 = fminf(fmaxf(y1, 0.f), 1023.f);
  x2 = fminf(fmaxf(x2, 0.f), 1023.f);
  y2 = fminf(fmaxf(y2, 0.f), 1023.f);
}

__device__ __forceinline__ uint32_t f2ord(float f) {
  uint32_t u = __float_as_uint(f);
  return (u & 0x80000000u) ? ~u : (u | 0x80000000u);
}
__device__ __forceinline__ float ord2f(uint32_t u) {
  return (u & 0x80000000u) ? __uint_as_float(u ^ 0x80000000u) : __uint_as_float(~u);
}

// Kernel 1: masked ordered score keys, coalesced linear write keys[t]
__global__ void k_score(const float* __restrict__ labels, const float* __restrict__ bbox,
                        uint32_t* __restrict__ keys) {
  int t = blockIdx.x * 256 + threadIdx.x;
  if (t >= TOTAL) return;
  int pos = t & (HW - 1);
  int ba  = t >> 12;
  int a = ba % 9, b = ba / 9;
  float score = labels[((b * 18 + 2 * a + 1) << 12) + pos];
  const float* dp = bbox + ((b * 36 + 4 * a) << 12) + pos;
  float d0 = dp[0], d1 = dp[4096], d2 = dp[8192], d3 = dp[12288];
  int y = pos >> 6, x = pos & 63;
  float x1, y1, x2, y2;
  decode_box(a, x, y, d0, d1, d2, d3, x1, y1, x2, y2);
  bool keep = (x2 - x1 + 1.f >= 16.f) && (y2 - y1 + 1.f >= 16.f);
  float s = keep ? score : -INFINITY;
  keys[t] = f2ord(s);
}

// Kernel 2: per-batch LDS histogram + suffix scan for top-2000 threshold bin
// + compaction. 16 blocks x 1024.
__global__ __launch_bounds__(1024) void k_batch(const uint32_t* __restrict__ keys,
                                                ull* __restrict__ selKeys,
                                                uint32_t* __restrict__ counters) {
  int b = blockIdx.x, tid = threadIdx.x;
  int wave = tid >> 6, lane = tid & 63;
  __shared__ uint32_t hist[HBINS];         // 32 KB
  __shared__ uint32_t wtot[16];
  __shared__ uint32_t sh_T, sh_cnt;
  const uint32_t* kb = keys + b * NANCH;
#pragma unroll
  for (int k = 0; k < HBINS / 1024; ++k) hist[k * 1024 + tid] = 0u;
  if (tid == 0) { sh_T = 0u; sh_cnt = 0u; }
  __syncthreads();
  for (int i = tid; i < NANCH; i += 1024) {
    uint32_t u = kb[i];
    if (u & 0x80000000u) atomicAdd(&hist[u >> (32 - HBITS)], 1u);
  }
  __syncthreads();
  uint32_t c[8], suf[8];
#pragma unroll
  for (int k = 0; k < 8; ++k) c[k] = hist[tid * 8 + k];
  suf[7] = c[7];
#pragma unroll
  for (int k = 6; k >= 0; --k) suf[k] = c[k] + suf[k + 1];
  uint32_t total = suf[0];
  uint32_t wsuf = total;
#pragma unroll
  for (int off = 1; off < 64; off <<= 1) {
    uint32_t v = __shfl_down(wsuf, off);
    if (lane + off < 64) wsuf += v;
  }
  if (lane == 0) wtot[wave] = wsuf;
  __syncthreads();
  uint32_t wab = 0;
  for (int w = wave + 1; w < 16; ++w) wab += wtot[w];
  uint32_t ssum = wsuf + wab;          // keys in bins >= 8*tid
  uint32_t above_t = ssum - total;     // keys in bins >= 8*(tid+1)
  if (above_t < TOPN && ssum >= TOPN) {
    uint32_t T = (uint32_t)(tid * 8);
#pragma unroll
    for (int k = 7; k >= 0; --k) {
      uint32_t ab = above_t + ((k < 7) ? suf[k + 1] : 0u);
      if (ab < TOPN && ab + c[k] >= TOPN) T = (uint32_t)(tid * 8 + k);
    }
    sh_T = T;
  }
  __syncthreads();
  uint32_t T = sh_T;
  for (int i = tid; i < NANCH; i += 1024) {
    uint32_t u = kb[i];
    if ((u >> (32 - HBITS)) >= T) {
      uint32_t slot = atomicAdd(&sh_cnt, 1u);
      if (slot < SELPAD) {
        uint32_t canon = (uint32_t)((i & 4095) * 9 + (i >> 12));  // pos*9 + a
        selKeys[b * SELPAD + slot] = (((ull)(~u)) << 32) | canon;
      }
    }
  }
  __syncthreads();
  if (tid == 0) counters[b] = (sh_cnt < SELPAD) ? sh_cnt : SELPAD;
}

// Kernel 3: rank-by-counting + decode + scatter of box/area/score to rank.
__global__ __launch_bounds__(256) void k_rank(const ull* __restrict__ selKeys,
                        const uint32_t* __restrict__ counters, const float* __restrict__ bbox,
                        float4* __restrict__ boxes, float* __restrict__ areas,
                        float* __restrict__ selScore) {
  int b = blockIdx.y;
  int i = blockIdx.x * 256 + threadIdx.x;
  int tid = threadIdx.x;
  uint32_t n = counters[b];
  const ull* sk = selKeys + b * SELPAD;
  ull ki = (i < (int)n) ? sk[i] : ~0ull;
  int rank = 0;
  __shared__ ull chunk[256];
  for (uint32_t base = 0; base < n; base += 256) {
    uint32_t j = base + (uint32_t)tid;
    chunk[tid] = (j < n) ? sk[j] : ~0ull;
    __syncthreads();
    int lim = (int)(n - base < 256u ? n - base : 256u);
    for (int t2 = 0; t2 < lim; ++t2) rank += (chunk[t2] < ki) ? 1 : 0;
    __syncthreads();
  }
  if (i < (int)n && rank < TOPN) {
    uint32_t idx = (uint32_t)ki;
    selScore[b * TOPN + rank] = ord2f(~((uint32_t)(ki >> 32)));
    int pos = (int)idx / 9, a = (int)idx - 9 * pos;
    int y = pos >> 6, x = pos & 63;
    const float* dp = bbox + ((b * 36 + 4 * a) << 12) + pos;
    float d0 = dp[0], d1 = dp[4096], d2 = dp[8192], d3 = dp[12288];
    float x1, y1, x2, y2;
    decode_box(a, x, y, d0, d1, d2, d3, x1, y1, x2, y2);
    boxes[b * PADN + rank] = make_float4(x1, y1, x2, y2);
    areas[b * PADN + rank] = (x2 - x1 + 1.f) * (y2 - y1 + 1.f);
  }
}

// Kernel 4: per-batch NMS. Phase A (parallel, 256 thr): 512x512 upper-tri
// suppression bitmask in LDS (pitch-17 rows, conflict-free). Phase B (1 wave):
// cheap greedy scan — prefetched LDS mask row + shfl bit test + OR per
// iteration, exact early exit at 300 kept. Exact fallback (direct test vs kept
// list) for candidates >= MNMS, should the scan ever get that far.
__global__ __launch_bounds__(256) void k_nms(const float4* __restrict__ boxes,
                                             const float* __restrict__ areas,
                                             const float* __restrict__ selScore,
                                             float* __restrict__ out) {
  int b = blockIdx.x, tid = threadIdx.x;
  int wave = tid >> 6, lane = tid & 63;
  __shared__ float sx1[MNMS], sy1[MNMS], sx2[MNMS], sy2[MNMS], sar[MNMS]; // 10 KB
  __shared__ uint32_t mrow[MNMS][MPITCH];                                 // 34.8 KB
  __shared__ int kidx[OUTN];
  __shared__ int sh_cnt;
  // stage first MNMS ranked candidates (SoA)
  for (int i = tid; i < MNMS; i += 256) {
    float4 v = boxes[b * PADN + i];
    sx1[i] = v.x; sy1[i] = v.y; sx2[i] = v.z; sy2[i] = v.w;
    sar[i] = areas[b * PADN + i];
  }
  __syncthreads();
  // Phase A: mask matrix. Thread t computes rows t and 511-t (balanced).
  const double MD = MIDC;
#pragma unroll
  for (int r = 0; r < 2; ++r) {
    int i = (r == 0) ? tid : (MNMS - 1 - tid);
    float ix1 = sx1[i], iy1 = sy1[i], ix2 = sx2[i], iy2 = sy2[i], ia = sar[i];
    int wlo = i >> 5;
    for (int w = 0; w < wlo; ++w) mrow[i][w] = 0u;
    for (int w = wlo; w < MW; ++w) {
      uint32_t bits = 0u;
      int jbase = w << 5;
      for (int jj = 0; jj < 32; ++jj) {
        int j = jbase + jj;
        if (j > i) {
          float iw = fminf(ix2, sx2[j]) - fmaxf(ix1, sx1[j]) + 1.f; iw = fmaxf(iw, 0.f);
          float ih = fminf(iy2, sy2[j]) - fmaxf(iy1, sy1[j]) + 1.f; ih = fmaxf(ih, 0.f);
          float inter = iw * ih;
          float uu = (ia + sar[j]) - inter;
          if ((double)inter >= MD * (double)uu) bits |= (1u << jj);
        }
      }
      mrow[i][w] = bits;
    }
  }
  __syncthreads();
  // Phase B: single-wave greedy scan
  if (wave == 0) {
    int l16 = lane & 15;
    uint32_t supw = 0u;         // lane l holds bitmap word (l&15); shfl reads l<16
    int cnt = 0;
    uint32_t pf[GDN];
#pragma unroll
    for (int ph = 0; ph < GDN; ++ph) pf[ph] = mrow[ph][l16];
    for (int base = 0; base < MNMS && cnt < OUTN; base += GDN) {
#pragma unroll
      for (int ph = 0; ph < GDN; ++ph) {
        int i = base + ph;
        uint32_t sw = __shfl(supw, i >> 5);
        if (!((sw >> (i & 31)) & 1u)) {          // uniform
          supw |= pf[ph];
          if (lane == 0 && cnt < OUTN) kidx[cnt] = i;
          cnt++;
        }
        int nx = i + GDN; if (nx > MNMS - 1) nx = MNMS - 1;
        pf[ph] = mrow[nx][l16];                  // prefetch
      }
    }
    // exact fallback: candidates beyond the mask matrix (rare/never)
    for (int i = MNMS; i < TOPN && cnt < OUTN; ++i) {
      float4 bi = boxes[b * PADN + i];
      float ia = areas[b * PADN + i];
      bool sup = false;
      for (int cb = 0; cb < cnt; cb += 64) {
        int k = cb + lane;
        if (k < cnt) {
          int kj = kidx[k];
          float4 bk = boxes[b * PADN + kj];
          float ka = areas[b * PADN + kj];
          float iw = fminf(bi.z, bk.z) - fmaxf(bi.x, bk.x) + 1.f; iw = fmaxf(iw, 0.f);
          float ih = fminf(bi.w, bk.w) - fmaxf(bi.y, bk.y) + 1.f; ih = fmaxf(ih, 0.f);
          float inter = iw * ih;
          float uu = (ia + ka) - inter;
          sup = sup || ((double)inter >= MD * (double)uu);
        }
      }
      if (!__any(sup)) {
        if (lane == 0) kidx[cnt] = i;
        cnt++;
      }
    }
    if (lane == 0) sh_cnt = (cnt < OUTN) ? cnt : OUTN;
  }
  __syncthreads();
  int c = sh_cnt;
  float4* ob = (float4*)out;
  for (int s2 = tid; s2 < OUTN; s2 += 256) {
    float4 bx = make_float4(0.f, 0.f, 0.f, 0.f);
    float sc = 0.f;
    if (s2 < c) {
      int i = kidx[s2];
      bx = boxes[b * PADN + i];
      sc = selScore[b * TOPN + i];
    }
    ob[b * OUTN + s2] = bx;
    out[NB * OUTN * 4 + b * OUTN + s2] = sc;
  }
}

extern "C" void kernel_launch(void* const* d_in, const int* in_sizes, int n_in,
                              void* d_out, int out_size, void* d_ws, size_t ws_size,
                              hipStream_t stream) {
  const float* labels = (const float*)d_in[0];  // (16, 18, 64, 64)
  const float* bbox   = (const float*)d_in[1];  // (16, 36, 64, 64)
  char* ws = (char*)d_ws;
  // workspace layout (bytes):
  uint32_t* keys    = (uint32_t*)(ws + 0);         // 589824*4   = 2,359,296
  ull* selKeys      = (ull*)(ws + 2359296);        // 16*3072*8  =   393,216
  float* selScore   = (float*)(ws + 2752512);      // 16*2000*4  =   128,000
  float* areas      = (float*)(ws + 2880512);      // 16*2048*4  =   131,072
  float4* boxes     = (float4*)(ws + 3011584);     // 16*2048*16 =   524,288
  uint32_t* counters= (uint32_t*)(ws + 3535872);   // 64
  float* out = (float*)d_out;

  hipLaunchKernelGGL(k_score, dim3((TOTAL + 255) / 256), dim3(256), 0, stream, labels, bbox, keys);
  hipLaunchKernelGGL(k_batch, dim3(NB), dim3(1024), 0, stream, keys, selKeys, counters);
  hipLaunchKernelGGL(k_rank,  dim3(SELPAD / 256, NB), dim3(256), 0, stream, selKeys, counters, bbox, boxes, areas, selScore);
  hipLaunchKernelGGL(k_nms,   dim3(NB), dim3(256), 0, stream, boxes, areas, selScore, out);
}

// Round 13
// 114.924 us; speedup vs baseline: 2.7604x; 1.3800x over previous
//
#include <hip/hip_runtime.h>
#include <stdint.h>

// Match numpy's unfused mul/add rounding everywhere (no FMA contraction).
#pragma clang fp contract(off)

typedef unsigned long long ull;

// Problem constants (B=16, H=W=64, A=9, stride 16, img 1024x1024)
#define NB 16
#define NA 9
#define HW 4096
#define NANCH (NA*HW)         // 36864
#define TOTAL (NB*NANCH)      // 589824
#define TOPN 2000
#define PADN 2048             // box/area buffer stride
#define SELPAD 3072           // candidate buffer per batch
#define OUTN 300
#define HBITS 13
#define HBINS (1 << HBITS)    // 8192 LDS histogram bins
#define MNMS 512              // mask-matrix extent (scan provably ends ~310)
#define MW 16                 // u32 words per mask row (512 bits)
#define MPITCH 17             // padded pitch (bank-conflict-free)
#define GDN 8                 // scan prefetch depth

// exact: RN32(inter/u) > 0.7f  <=>  (double)inter >= MIDC*(double)u
// 0.7f = 0x1.666666p-1; next = 0x1.666668p-1; midpoint = 0x1.666667p-1 exactly
// representable in double; 25x24-bit product exact; tie-to-even rounds to the
// even (0.7f) side, so '>' at the midpoint is false — '>=' reproduces it.
// (HW-verified: absmax 0 in rounds 9-12.)
#define MIDC 0x1.666667p-1

// 9 base anchors (x1,y1,x2,y2), computed exactly per the numpy generator
__constant__ float c_ax1[9] = {-3.5f,-15.f,-38.f,  0.f, -8.f,-24.f,  2.5f, -3.f,-14.f};
__constant__ float c_ay1[9] = { 2.f,  -4.f,-16.f,  0.f, -8.f,-24.f, -3.f,-14.f,-36.f};
__constant__ float c_ax2[9] = {18.5f, 30.f, 53.f, 15.f, 23.f, 39.f, 12.5f, 18.f, 29.f};
__constant__ float c_ay2[9] = {13.f,  19.f, 31.f, 15.f, 23.f, 39.f, 18.f,  29.f, 51.f};

__device__ __forceinline__ void decode_box(int a, int x, int y,
    float d0, float d1, float d2, float d3,
    float& x1, float& y1, float& x2, float& y2) {
  float ax1 = c_ax1[a] + 16.f * (float)x;
  float ay1 = c_ay1[a] + 16.f * (float)y;
  float ax2 = c_ax2[a] + 16.f * (float)x;
  float ay2 = c_ay2[a] + 16.f * (float)y;
  float aw  = ax2 - ax1 + 1.f;
  float ah  = ay2 - ay1 + 1.f;
  float acx = ax1 + 0.5f * aw;
  float acy = ay1 + 0.5f * ah;
  float cx = d0 * aw + acx;
  float cy = d1 * ah + acy;
  float pw = expf(d2) * aw;
  float ph = expf(d3) * ah;
  x1 = cx - 0.5f * pw;
  y1 = cy - 0.5f * ph;
  x2 = cx + 0.5f * pw;
  y2 = cy + 0.5f * ph;
  x1 = fminf(fmaxf(x1, 0.f), 1023.f);
  y1 = fminf(fmaxf(y1, 0.f), 1023.f);
  x2 = fminf(fmaxf(x2, 0.f), 1023.f);
  y2 = fminf(fmaxf(y2, 0.f), 1023.f);
}

__device__ __forceinline__ uint32_t f2ord(float f) {
  uint32_t u = __float_as_uint(f);
  return (u & 0x80000000u) ? ~u : (u | 0x80000000u);
}
__device__ __forceinline__ float ord2f(uint32_t u) {
  return (u & 0x80000000u) ? __uint_as_float(u ^ 0x80000000u) : __uint_as_float(~u);
}

// Kernel 1: masked ordered score keys, coalesced linear write keys[t]
__global__ void k_score(const float* __restrict__ labels, const float* __restrict__ bbox,
                        uint32_t* __restrict__ keys) {
  int t = blockIdx.x * 256 + threadIdx.x;
  if (t >= TOTAL) return;
  int pos = t & (HW - 1);
  int ba  = t >> 12;
  int a = ba % 9, b = ba / 9;
  float score = labels[((b * 18 + 2 * a + 1) << 12) + pos];
  const float* dp = bbox + ((b * 36 + 4 * a) << 12) + pos;
  float d0 = dp[0], d1 = dp[4096], d2 = dp[8192], d3 = dp[12288];
  int y = pos >> 6, x = pos & 63;
  float x1, y1, x2, y2;
  decode_box(a, x, y, d0, d1, d2, d3, x1, y1, x2, y2);
  bool keep = (x2 - x1 + 1.f >= 16.f) && (y2 - y1 + 1.f >= 16.f);
  float s = keep ? score : -INFINITY;
  keys[t] = f2ord(s);
}

// Kernel 2: per-batch LDS histogram + suffix scan for top-2000 threshold bin
// + compaction. 16 blocks x 1024.
__global__ __launch_bounds__(1024) void k_batch(const uint32_t* __restrict__ keys,
                                                ull* __restrict__ selKeys,
                                                uint32_t* __restrict__ counters) {
  int b = blockIdx.x, tid = threadIdx.x;
  int wave = tid >> 6, lane = tid & 63;
  __shared__ uint32_t hist[HBINS];         // 32 KB
  __shared__ uint32_t wtot[16];
  __shared__ uint32_t sh_T, sh_cnt;
  const uint32_t* kb = keys + b * NANCH;
#pragma unroll
  for (int k = 0; k < HBINS / 1024; ++k) hist[k * 1024 + tid] = 0u;
  if (tid == 0) { sh_T = 0u; sh_cnt = 0u; }
  __syncthreads();
  for (int i = tid; i < NANCH; i += 1024) {
    uint32_t u = kb[i];
    if (u & 0x80000000u) atomicAdd(&hist[u >> (32 - HBITS)], 1u);
  }
  __syncthreads();
  uint32_t c[8], suf[8];
#pragma unroll
  for (int k = 0; k < 8; ++k) c[k] = hist[tid * 8 + k];
  suf[7] = c[7];
#pragma unroll
  for (int k = 6; k >= 0; --k) suf[k] = c[k] + suf[k + 1];
  uint32_t total = suf[0];
  uint32_t wsuf = total;
#pragma unroll
  for (int off = 1; off < 64; off <<= 1) {
    uint32_t v = __shfl_down(wsuf, off);
    if (lane + off < 64) wsuf += v;
  }
  if (lane == 0) wtot[wave] = wsuf;
  __syncthreads();
  uint32_t wab = 0;
  for (int w = wave + 1; w < 16; ++w) wab += wtot[w];
  uint32_t ssum = wsuf + wab;          // keys in bins >= 8*tid
  uint32_t above_t = ssum - total;     // keys in bins >= 8*(tid+1)
  if (above_t < TOPN && ssum >= TOPN) {
    uint32_t T = (uint32_t)(tid * 8);
#pragma unroll
    for (int k = 7; k >= 0; --k) {
      uint32_t ab = above_t + ((k < 7) ? suf[k + 1] : 0u);
      if (ab < TOPN && ab + c[k] >= TOPN) T = (uint32_t)(tid * 8 + k);
    }
    sh_T = T;
  }
  __syncthreads();
  uint32_t T = sh_T;
  for (int i = tid; i < NANCH; i += 1024) {
    uint32_t u = kb[i];
    if ((u >> (32 - HBITS)) >= T) {
      uint32_t slot = atomicAdd(&sh_cnt, 1u);
      if (slot < SELPAD) {
        uint32_t canon = (uint32_t)((i & 4095) * 9 + (i >> 12));  // pos*9 + a
        selKeys[b * SELPAD + slot] = (((ull)(~u)) << 32) | canon;
      }
    }
  }
  __syncthreads();
  if (tid == 0) counters[b] = (sh_cnt < SELPAD) ? sh_cnt : SELPAD;
}

// Kernel 3: rank-by-counting + decode + scatter of box/area/score to rank.
__global__ __launch_bounds__(256) void k_rank(const ull* __restrict__ selKeys,
                        const uint32_t* __restrict__ counters, const float* __restrict__ bbox,
                        float4* __restrict__ boxes, float* __restrict__ areas,
                        float* __restrict__ selScore) {
  int b = blockIdx.y;
  int i = blockIdx.x * 256 + threadIdx.x;
  int tid = threadIdx.x;
  uint32_t n = counters[b];
  const ull* sk = selKeys + b * SELPAD;
  ull ki = (i < (int)n) ? sk[i] : ~0ull;
  int rank = 0;
  __shared__ ull chunk[256];
  for (uint32_t base = 0; base < n; base += 256) {
    uint32_t j = base + (uint32_t)tid;
    chunk[tid] = (j < n) ? sk[j] : ~0ull;
    __syncthreads();
    int lim = (int)(n - base < 256u ? n - base : 256u);
    for (int t2 = 0; t2 < lim; ++t2) rank += (chunk[t2] < ki) ? 1 : 0;
    __syncthreads();
  }
  if (i < (int)n && rank < TOPN) {
    uint32_t idx = (uint32_t)ki;
    selScore[b * TOPN + rank] = ord2f(~((uint32_t)(ki >> 32)));
    int pos = (int)idx / 9, a = (int)idx - 9 * pos;
    int y = pos >> 6, x = pos & 63;
    const float* dp = bbox + ((b * 36 + 4 * a) << 12) + pos;
    float d0 = dp[0], d1 = dp[4096], d2 = dp[8192], d3 = dp[12288];
    float x1, y1, x2, y2;
    decode_box(a, x, y, d0, d1, d2, d3, x1, y1, x2, y2);
    boxes[b * PADN + rank] = make_float4(x1, y1, x2, y2);
    areas[b * PADN + rank] = (x2 - x1 + 1.f) * (y2 - y1 + 1.f);
  }
}

// Kernel 4: per-batch NMS, 1024 threads (16 waves -> 4/SIMD latency hiding).
// Phase A: 8192 word-tasks (i = k&511, w = k>>9): consecutive lanes take
// consecutive rows (stride-1 LDS row reads, broadcast column reads); lower-tri
// words -> 0; diagonal word via branch-free bit mask. Phase B: single-wave
// greedy scan with ballot-based bit test (no shfl chain) + prefetch, exact
// early exit at 300 kept. Exact fallback for candidates >= MNMS.
__global__ __launch_bounds__(1024) void k_nms(const float4* __restrict__ boxes,
                                              const float* __restrict__ areas,
                                              const float* __restrict__ selScore,
                                              float* __restrict__ out) {
  int b = blockIdx.x, tid = threadIdx.x;
  __shared__ float sx1[MNMS], sy1[MNMS], sx2[MNMS], sy2[MNMS], sar[MNMS]; // 10 KB
  __shared__ uint32_t mrow[MNMS][MPITCH];                                 // 34.8 KB
  __shared__ int kidx[OUTN];
  __shared__ int sh_cnt;
  // stage first MNMS ranked candidates (SoA)
  if (tid < MNMS) {
    float4 v = boxes[b * PADN + tid];
    sx1[tid] = v.x; sy1[tid] = v.y; sx2[tid] = v.z; sy2[tid] = v.w;
    sar[tid] = areas[b * PADN + tid];
  }
  __syncthreads();
  const double MD = MIDC;
  // Phase A: mask matrix, 8 word-tasks per thread
#pragma unroll
  for (int p = 0; p < 8; ++p) {
    int k = p * 1024 + tid;
    int i = k & (MNMS - 1);
    int w = k >> 9;                    // 0..15
    int iw5 = i >> 5;
    if (w < iw5) { mrow[i][w] = 0u; continue; }
    uint32_t vmask = 0xFFFFFFFFu;
    if (w == iw5) {
      int r = i & 31;
      vmask = (r == 31) ? 0u : (0xFFFFFFFFu << (r + 1));
    }
    uint32_t bits = 0u;
    if (vmask) {
      float ix1 = sx1[i], iy1 = sy1[i], ix2 = sx2[i], iy2 = sy2[i], ia = sar[i];
      int jbase = w << 5;
#pragma unroll
      for (int jj = 0; jj < 32; ++jj) {
        int j = jbase + jj;
        float iw_ = fminf(ix2, sx2[j]) - fmaxf(ix1, sx1[j]) + 1.f; iw_ = fmaxf(iw_, 0.f);
        float ih_ = fminf(iy2, sy2[j]) - fmaxf(iy1, sy1[j]) + 1.f; ih_ = fmaxf(ih_, 0.f);
        float inter = iw_ * ih_;
        float uu = (ia + sar[j]) - inter;
        if ((double)inter >= MD * (double)uu) bits |= (1u << jj);
      }
    }
    mrow[i][w] = bits & vmask;
  }
  __syncthreads();
  // Phase B: single-wave greedy scan (ballot bit test; lane l owns word l&15)
  if (tid < 64) {
    int lane = tid;
    int l16 = lane & 15;
    uint32_t supw = 0u;
    int cnt = 0;
    uint32_t pf[GDN];
#pragma unroll
    for (int ph = 0; ph < GDN; ++ph) pf[ph] = mrow[ph][l16];
    for (int base = 0; base < MNMS && cnt < OUTN; base += GDN) {
#pragma unroll
      for (int ph = 0; ph < GDN; ++ph) {
        int i = base + ph;
        ull bal = __ballot(((supw >> (i & 31)) & 1u) != 0u);
        if (!((bal >> (i >> 5)) & 1ull)) {       // uniform (lane i>>5 owns word)
          supw |= pf[ph];
          if (lane == 0 && cnt < OUTN) kidx[cnt] = i;
          cnt++;
        }
        int nx = i + GDN; if (nx > MNMS - 1) nx = MNMS - 1;
        pf[ph] = mrow[nx][l16];                  // prefetch
      }
    }
    // exact fallback: candidates beyond the mask matrix (rare/never)
    for (int i = MNMS; i < TOPN && cnt < OUTN; ++i) {
      float4 bi = boxes[b * PADN + i];
      float ia = areas[b * PADN + i];
      bool sup = false;
      for (int cb = 0; cb < cnt; cb += 64) {
        int k = cb + lane;
        if (k < cnt) {
          int kj = kidx[k];
          float4 bk = boxes[b * PADN + kj];
          float ka = areas[b * PADN + kj];
          float iw = fminf(bi.z, bk.z) - fmaxf(bi.x, bk.x) + 1.f; iw = fmaxf(iw, 0.f);
          float ih = fminf(bi.w, bk.w) - fmaxf(bi.y, bk.y) + 1.f; ih = fmaxf(ih, 0.f);
          float inter = iw * ih;
          float uu = (ia + ka) - inter;
          sup = sup || ((double)inter >= MD * (double)uu);
        }
      }
      if (!__any(sup)) {
        if (lane == 0) kidx[cnt] = i;
        cnt++;
      }
    }
    if (lane == 0) sh_cnt = (cnt < OUTN) ? cnt : OUTN;
  }
  __syncthreads();
  int c = sh_cnt;
  float4* ob = (float4*)out;
  for (int s2 = tid; s2 < OUTN; s2 += 1024) {
    float4 bx = make_float4(0.f, 0.f, 0.f, 0.f);
    float sc = 0.f;
    if (s2 < c) {
      int i = kidx[s2];
      bx = boxes[b * PADN + i];
      sc = selScore[b * TOPN + i];
    }
    ob[b * OUTN + s2] = bx;
    out[NB * OUTN * 4 + b * OUTN + s2] = sc;
  }
}

extern "C" void kernel_launch(void* const* d_in, const int* in_sizes, int n_in,
                              void* d_out, int out_size, void* d_ws, size_t ws_size,
                              hipStream_t stream) {
  const float* labels = (const float*)d_in[0];  // (16, 18, 64, 64)
  const float* bbox   = (const float*)d_in[1];  // (16, 36, 64, 64)
  char* ws = (char*)d_ws;
  // workspace layout (bytes):
  uint32_t* keys    = (uint32_t*)(ws + 0);         // 589824*4   = 2,359,296
  ull* selKeys      = (ull*)(ws + 2359296);        // 16*3072*8  =   393,216
  float* selScore   = (float*)(ws + 2752512);      // 16*2000*4  =   128,000
  float* areas      = (float*)(ws + 2880512);      // 16*2048*4  =   131,072
  float4* boxes     = (float4*)(ws + 3011584);     // 16*2048*16 =   524,288
  uint32_t* counters= (uint32_t*)(ws + 3535872);   // 64
  float* out = (float*)d_out;

  hipLaunchKernelGGL(k_score, dim3((TOTAL + 255) / 256), dim3(256), 0, stream, labels, bbox, keys);
  hipLaunchKernelGGL(k_batch, dim3(NB), dim3(1024), 0, stream, keys, selKeys, counters);
  hipLaunchKernelGGL(k_rank,  dim3(SELPAD / 256, NB), dim3(256), 0, stream, selKeys, counters, bbox, boxes, areas, selScore);
  hipLaunchKernelGGL(k_nms,   dim3(NB), dim3(1024), 0, stream, boxes, areas, selScore, out);
}

// Round 14
// 99.992 us; speedup vs baseline: 3.1726x; 1.1493x over previous
//
#include <hip/hip_runtime.h>
#include <stdint.h>

// Match numpy's unfused mul/add rounding everywhere (no FMA contraction).
#pragma clang fp contract(off)

typedef unsigned long long ull;

// Problem constants (B=16, H=W=64, A=9, stride 16, img 1024x1024)
#define NB 16
#define NA 9
#define HW 4096
#define NANCH (NA*HW)         // 36864
#define TOTAL (NB*NANCH)      // 589824
#define TOPN 2000
#define PADN 2048             // box/area buffer stride
#define SELPAD 3072           // candidate buffer per batch
#define OUTN 300
#define HBITS 13
#define HBINS (1 << HBITS)    // 8192 LDS histogram bins
#define MNMS 384              // mask extent (scan ends ~310; exact fallback past it)
#define MSTRIPS (MNMS/64)     // 6 ull words per row
#define GDN 8                 // scan prefetch depth

// exact: RN32(inter/u) > 0.7f  <=>  (double)inter >= MIDC*(double)u
// 0.7f = 0x1.666666p-1; next = 0x1.666668p-1; midpoint = 0x1.666667p-1 exactly
// representable in double; 25x24-bit product exact; tie-to-even rounds to the
// even (0.7f) side, so '>' at the midpoint is false — '>=' reproduces it.
// (HW-verified: absmax 0 in rounds 9-13.)
#define MIDC 0x1.666667p-1

// 9 base anchors (x1,y1,x2,y2), computed exactly per the numpy generator
__constant__ float c_ax1[9] = {-3.5f,-15.f,-38.f,  0.f, -8.f,-24.f,  2.5f, -3.f,-14.f};
__constant__ float c_ay1[9] = { 2.f,  -4.f,-16.f,  0.f, -8.f,-24.f, -3.f,-14.f,-36.f};
__constant__ float c_ax2[9] = {18.5f, 30.f, 53.f, 15.f, 23.f, 39.f, 12.5f, 18.f, 29.f};
__constant__ float c_ay2[9] = {13.f,  19.f, 31.f, 15.f, 23.f, 39.f, 18.f,  29.f, 51.f};

__device__ __forceinline__ void decode_box(int a, int x, int y,
    float d0, float d1, float d2, float d3,
    float& x1, float& y1, float& x2, float& y2) {
  float ax1 = c_ax1[a] + 16.f * (float)x;
  float ay1 = c_ay1[a] + 16.f * (float)y;
  float ax2 = c_ax2[a] + 16.f * (float)x;
  float ay2 = c_ay2[a] + 16.f * (float)y;
  float aw  = ax2 - ax1 + 1.f;
  float ah  = ay2 - ay1 + 1.f;
  float acx = ax1 + 0.5f * aw;
  float acy = ay1 + 0.5f * ah;
  float cx = d0 * aw + acx;
  float cy = d1 * ah + acy;
  float pw = expf(d2) * aw;
  float ph = expf(d3) * ah;
  x1 = cx - 0.5f * pw;
  y1 = cy - 0.5f * ph;
  x2 = cx + 0.5f * pw;
  y2 = cy + 0.5f * ph;
  x1 = fminf(fmaxf(x1, 0.f), 1023.f);
  y1 = fminf(fmaxf(y1, 0.f), 1023.f);
  x2 = fminf(fmaxf(x2, 0.f), 1023.f);
  y2 = fminf(fmaxf(y2, 0.f), 1023.f);
}

__device__ __forceinline__ uint32_t f2ord(float f) {
  uint32_t u = __float_as_uint(f);
  return (u & 0x80000000u) ? ~u : (u | 0x80000000u);
}
__device__ __forceinline__ float ord2f(uint32_t u) {
  return (u & 0x80000000u) ? __uint_as_float(u ^ 0x80000000u) : __uint_as_float(~u);
}

// Kernel 1: masked ordered score keys, coalesced linear write keys[t]
__global__ void k_score(const float* __restrict__ labels, const float* __restrict__ bbox,
                        uint32_t* __restrict__ keys) {
  int t = blockIdx.x * 256 + threadIdx.x;
  if (t >= TOTAL) return;
  int pos = t & (HW - 1);
  int ba  = t >> 12;
  int a = ba % 9, b = ba / 9;
  float score = labels[((b * 18 + 2 * a + 1) << 12) + pos];
  const float* dp = bbox + ((b * 36 + 4 * a) << 12) + pos;
  float d0 = dp[0], d1 = dp[4096], d2 = dp[8192], d3 = dp[12288];
  int y = pos >> 6, x = pos & 63;
  float x1, y1, x2, y2;
  decode_box(a, x, y, d0, d1, d2, d3, x1, y1, x2, y2);
  bool keep = (x2 - x1 + 1.f >= 16.f) && (y2 - y1 + 1.f >= 16.f);
  float s = keep ? score : -INFINITY;
  keys[t] = f2ord(s);
}

// Kernel 2: per-batch LDS histogram + suffix scan for top-2000 threshold bin
// + compaction. 16 blocks x 1024. Global reads vectorized uint4.
__global__ __launch_bounds__(1024) void k_batch(const uint32_t* __restrict__ keys,
                                                ull* __restrict__ selKeys,
                                                uint32_t* __restrict__ counters) {
  int b = blockIdx.x, tid = threadIdx.x;
  int wave = tid >> 6, lane = tid & 63;
  __shared__ uint32_t hist[HBINS];         // 32 KB
  __shared__ uint32_t wtot[16];
  __shared__ uint32_t sh_T, sh_cnt;
  const uint32_t* kb = keys + b * NANCH;
  const uint4* kb4 = (const uint4*)kb;
#pragma unroll
  for (int k = 0; k < HBINS / 1024; ++k) hist[k * 1024 + tid] = 0u;
  if (tid == 0) { sh_T = 0u; sh_cnt = 0u; }
  __syncthreads();
  for (int i4 = tid; i4 < NANCH / 4; i4 += 1024) {
    uint4 v = kb4[i4];
    if (v.x & 0x80000000u) atomicAdd(&hist[v.x >> (32 - HBITS)], 1u);
    if (v.y & 0x80000000u) atomicAdd(&hist[v.y >> (32 - HBITS)], 1u);
    if (v.z & 0x80000000u) atomicAdd(&hist[v.z >> (32 - HBITS)], 1u);
    if (v.w & 0x80000000u) atomicAdd(&hist[v.w >> (32 - HBITS)], 1u);
  }
  __syncthreads();
  uint32_t c[8], suf[8];
#pragma unroll
  for (int k = 0; k < 8; ++k) c[k] = hist[tid * 8 + k];
  suf[7] = c[7];
#pragma unroll
  for (int k = 6; k >= 0; --k) suf[k] = c[k] + suf[k + 1];
  uint32_t total = suf[0];
  uint32_t wsuf = total;
#pragma unroll
  for (int off = 1; off < 64; off <<= 1) {
    uint32_t v = __shfl_down(wsuf, off);
    if (lane + off < 64) wsuf += v;
  }
  if (lane == 0) wtot[wave] = wsuf;
  __syncthreads();
  uint32_t wab = 0;
  for (int w = wave + 1; w < 16; ++w) wab += wtot[w];
  uint32_t ssum = wsuf + wab;          // keys in bins >= 8*tid
  uint32_t above_t = ssum - total;     // keys in bins >= 8*(tid+1)
  if (above_t < TOPN && ssum >= TOPN) {
    uint32_t T = (uint32_t)(tid * 8);
#pragma unroll
    for (int k = 7; k >= 0; --k) {
      uint32_t ab = above_t + ((k < 7) ? suf[k + 1] : 0u);
      if (ab < TOPN && ab + c[k] >= TOPN) T = (uint32_t)(tid * 8 + k);
    }
    sh_T = T;
  }
  __syncthreads();
  uint32_t T = sh_T;
  for (int i4 = tid; i4 < NANCH / 4; i4 += 1024) {
    uint4 v = kb4[i4];
    uint32_t vv[4] = { v.x, v.y, v.z, v.w };
#pragma unroll
    for (int cc = 0; cc < 4; ++cc) {
      uint32_t u = vv[cc];
      if ((u >> (32 - HBITS)) >= T) {
        uint32_t slot = atomicAdd(&sh_cnt, 1u);
        if (slot < SELPAD) {
          int i = i4 * 4 + cc;
          uint32_t canon = (uint32_t)((i & 4095) * 9 + (i >> 12));  // pos*9 + a
          selKeys[b * SELPAD + slot] = (((ull)(~u)) << 32) | canon;
        }
      }
    }
  }
  __syncthreads();
  if (tid == 0) counters[b] = (sh_cnt < SELPAD) ? sh_cnt : SELPAD;
}

// Kernel 3: rank-by-counting + decode + scatter of box/area/score to rank.
__global__ __launch_bounds__(256) void k_rank(const ull* __restrict__ selKeys,
                        const uint32_t* __restrict__ counters, const float* __restrict__ bbox,
                        float4* __restrict__ boxes, float* __restrict__ areas,
                        float* __restrict__ selScore) {
  int b = blockIdx.y;
  int i = blockIdx.x * 256 + threadIdx.x;
  int tid = threadIdx.x;
  uint32_t n = counters[b];
  const ull* sk = selKeys + b * SELPAD;
  ull ki = (i < (int)n) ? sk[i] : ~0ull;
  int rank = 0;
  __shared__ ull chunk[256];
  for (uint32_t base = 0; base < n; base += 256) {
    uint32_t j = base + (uint32_t)tid;
    chunk[tid] = (j < n) ? sk[j] : ~0ull;
    __syncthreads();
    int lim = (int)(n - base < 256u ? n - base : 256u);
    for (int t2 = 0; t2 < lim; ++t2) rank += (chunk[t2] < ki) ? 1 : 0;
    __syncthreads();
  }
  if (i < (int)n && rank < TOPN) {
    uint32_t idx = (uint32_t)ki;
    selScore[b * TOPN + rank] = ord2f(~((uint32_t)(ki >> 32)));
    int pos = (int)idx / 9, a = (int)idx - 9 * pos;
    int y = pos >> 6, x = pos & 63;
    const float* dp = bbox + ((b * 36 + 4 * a) << 12) + pos;
    float d0 = dp[0], d1 = dp[4096], d2 = dp[8192], d3 = dp[12288];
    float x1, y1, x2, y2;
    decode_box(a, x, y, d0, d1, d2, d3, x1, y1, x2, y2);
    boxes[b * PADN + rank] = make_float4(x1, y1, x2, y2);
    areas[b * PADN + rank] = (x2 - x1 + 1.f) * (y2 - y1 + 1.f);
  }
}

// Kernel 4: per-batch NMS, 1024 threads. Phase A: lane owns column j=64s+lane
// (box in registers); per row: 1 broadcast b128 + 1 b32 + ~16 VALU; the 64-bit
// mask word is built with ONE __ballot and stored by lane 0 — LDS-issue count
// drops ~8x vs per-lane scalar reads. Rows i of strip s generated for
// i < 64(s+1) (others are below-diagonal; Phase B masks words l < i>>6 to 0).
// Phase B: single-wave greedy scan, ballot bit test, GDN-deep prefetch, exact
// early exit at 300 kept. Exact fallback (vs kept list) for candidates >= MNMS.
__global__ __launch_bounds__(1024) void k_nms(const float4* __restrict__ boxes,
                                              const float* __restrict__ areas,
                                              const float* __restrict__ selScore,
                                              float* __restrict__ out) {
  int b = blockIdx.x, tid = threadIdx.x;
  int wv = tid >> 6, lane = tid & 63;
  __shared__ float4 sbox[MNMS];           // 6 KB
  __shared__ float  sar[MNMS];            // 1.5 KB
  __shared__ ull    mrowU[MNMS][8];       // 24 KB (words 0..5 used, pitch 8)
  __shared__ int    kidx[OUTN];
  __shared__ int    sh_cnt;
  if (tid < MNMS) {
    sbox[tid] = boxes[b * PADN + tid];
    sar[tid]  = areas[b * PADN + tid];
  }
  __syncthreads();
  const double MD = MIDC;
  // Phase A: 6 strips; wave wv handles rows i == wv (mod 16)
#pragma unroll
  for (int s = 0; s < MSTRIPS; ++s) {
    int j = (s << 6) + lane;
    float4 bj = sbox[j];
    float  ja = sar[j];
    int rmax = (s + 1) << 6; if (rmax > MNMS) rmax = MNMS;
    for (int i = wv; i < rmax; i += 16) {
      float4 bi = sbox[i];
      float  ia = sar[i];
      float iw = fminf(bi.z, bj.z) - fmaxf(bi.x, bj.x) + 1.f; iw = fmaxf(iw, 0.f);
      float ih = fminf(bi.w, bj.w) - fmaxf(bi.y, bj.y) + 1.f; ih = fmaxf(ih, 0.f);
      float inter = iw * ih;
      float uu = (ia + ja) - inter;
      bool sup = (j > i) && ((double)inter >= MD * (double)uu);
      ull mb = __ballot(sup);
      if (lane == 0) mrowU[i][s] = mb;
    }
  }
  __syncthreads();
  // Phase B: single-wave greedy scan (lane l8 owns 64-bit word l8)
  if (tid < 64) {
    int l8 = lane & 7;
    ull supw = 0ull;
    int cnt = 0;
    ull pf[GDN];
#pragma unroll
    for (int ph = 0; ph < GDN; ++ph) pf[ph] = mrowU[ph][l8];
    for (int base = 0; base < MNMS && cnt < OUTN; base += GDN) {
#pragma unroll
      for (int ph = 0; ph < GDN; ++ph) {
        int i = base + ph;
        ull bal = __ballot(((supw >> (i & 63)) & 1ull) != 0ull);
        if (!((bal >> (i >> 6)) & 1ull)) {       // uniform (lane i>>6 owns word)
          ull mm = (l8 >= (i >> 6) && l8 < MSTRIPS) ? pf[ph] : 0ull;
          supw |= mm;
          if (lane == 0 && cnt < OUTN) kidx[cnt] = i;
          cnt++;
        }
        int nx = i + GDN; if (nx > MNMS - 1) nx = MNMS - 1;
        pf[ph] = mrowU[nx][l8];                  // prefetch
      }
    }
    // exact fallback: candidates beyond the mask matrix (rare/never)
    for (int i = MNMS; i < TOPN && cnt < OUTN; ++i) {
      float4 bi = boxes[b * PADN + i];
      float ia = areas[b * PADN + i];
      bool sup = false;
      for (int cb = 0; cb < cnt; cb += 64) {
        int k = cb + lane;
        if (k < cnt) {
          int kj = kidx[k];
          float4 bk = boxes[b * PADN + kj];
          float ka = areas[b * PADN + kj];
          float iw = fminf(bi.z, bk.z) - fmaxf(bi.x, bk.x) + 1.f; iw = fmaxf(iw, 0.f);
          float ih = fminf(bi.w, bk.w) - fmaxf(bi.y, bk.y) + 1.f; ih = fmaxf(ih, 0.f);
          float inter = iw * ih;
          float uu = (ia + ka) - inter;
          sup = sup || ((double)inter >= MD * (double)uu);
        }
      }
      if (!__any(sup)) {
        if (lane == 0) kidx[cnt] = i;
        cnt++;
      }
    }
    if (lane == 0) sh_cnt = (cnt < OUTN) ? cnt : OUTN;
  }
  __syncthreads();
  int c = sh_cnt;
  float4* ob = (float4*)out;
  for (int s2 = tid; s2 < OUTN; s2 += 1024) {
    float4 bx = make_float4(0.f, 0.f, 0.f, 0.f);
    float sc = 0.f;
    if (s2 < c) {
      int i = kidx[s2];
      bx = boxes[b * PADN + i];
      sc = selScore[b * TOPN + i];
    }
    ob[b * OUTN + s2] = bx;
    out[NB * OUTN * 4 + b * OUTN + s2] = sc;
  }
}

extern "C" void kernel_launch(void* const* d_in, const int* in_sizes, int n_in,
                              void* d_out, int out_size, void* d_ws, size_t ws_size,
                              hipStream_t stream) {
  const float* labels = (const float*)d_in[0];  // (16, 18, 64, 64)
  const float* bbox   = (const float*)d_in[1];  // (16, 36, 64, 64)
  char* ws = (char*)d_ws;
  // workspace layout (bytes):
  uint32_t* keys    = (uint32_t*)(ws + 0);         // 589824*4   = 2,359,296
  ull* selKeys      = (ull*)(ws + 2359296);        // 16*3072*8  =   393,216
  float* selScore   = (float*)(ws + 2752512);      // 16*2000*4  =   128,000
  float* areas      = (float*)(ws + 2880512);      // 16*2048*4  =   131,072
  float4* boxes     = (float4*)(ws + 3011584);     // 16*2048*16 =   524,288
  uint32_t* counters= (uint32_t*)(ws + 3535872);   // 64
  float* out = (float*)d_out;

  hipLaunchKernelGGL(k_score, dim3((TOTAL + 255) / 256), dim3(256), 0, stream, labels, bbox, keys);
  hipLaunchKernelGGL(k_batch, dim3(NB), dim3(1024), 0, stream, keys, selKeys, counters);
  hipLaunchKernelGGL(k_rank,  dim3(SELPAD / 256, NB), dim3(256), 0, stream, selKeys, counters, bbox, boxes, areas, selScore);
  hipLaunchKernelGGL(k_nms,   dim3(NB), dim3(1024), 0, stream, boxes, areas, selScore, out);
}

// Round 15
// 90.423 us; speedup vs baseline: 3.5083x; 1.1058x over previous
//
#include <hip/hip_runtime.h>
#include <stdint.h>

// Match numpy's unfused mul/add rounding everywhere (no FMA contraction).
#pragma clang fp contract(off)

typedef unsigned long long ull;

// Problem constants (B=16, H=W=64, A=9, stride 16, img 1024x1024)
#define NB 16
#define NA 9
#define HW 4096
#define NANCH (NA*HW)         // 36864
#define TOTAL (NB*NANCH)      // 589824
#define TOPN 2000
#define PADN 2048             // box/area buffer stride
#define SELPAD 3072           // candidate buffer per batch
#define OUTN 300
#define HBITS 13
#define HBINS (1 << HBITS)    // 8192 LDS histogram bins
#define MNMS 384              // mask extent (scan ends ~310; exact fallback past it)
#define MSTRIPS (MNMS/64)     // 6 ull words per row
#define MPITCH 8              // row pitch in ull words (64B-aligned rows)
#define GD2 16                // scan prefetch depth

// exact: RN32(inter/u) > 0.7f  <=>  (double)inter >= MIDC*(double)u
// 0.7f = 0x1.666666p-1; next = 0x1.666668p-1; midpoint = 0x1.666667p-1 exactly
// representable in double; 25x24-bit product exact; tie-to-even rounds to the
// even (0.7f) side, so '>' at the midpoint is false — '>=' reproduces it.
// (HW-verified: absmax 0 in rounds 9-14.)
#define MIDC 0x1.666667p-1

// 9 base anchors (x1,y1,x2,y2), computed exactly per the numpy generator
__constant__ float c_ax1[9] = {-3.5f,-15.f,-38.f,  0.f, -8.f,-24.f,  2.5f, -3.f,-14.f};
__constant__ float c_ay1[9] = { 2.f,  -4.f,-16.f,  0.f, -8.f,-24.f, -3.f,-14.f,-36.f};
__constant__ float c_ax2[9] = {18.5f, 30.f, 53.f, 15.f, 23.f, 39.f, 12.5f, 18.f, 29.f};
__constant__ float c_ay2[9] = {13.f,  19.f, 31.f, 15.f, 23.f, 39.f, 18.f,  29.f, 51.f};

__device__ __forceinline__ void decode_box(int a, int x, int y,
    float d0, float d1, float d2, float d3,
    float& x1, float& y1, float& x2, float& y2) {
  float ax1 = c_ax1[a] + 16.f * (float)x;
  float ay1 = c_ay1[a] + 16.f * (float)y;
  float ax2 = c_ax2[a] + 16.f * (float)x;
  float ay2 = c_ay2[a] + 16.f * (float)y;
  float aw  = ax2 - ax1 + 1.f;
  float ah  = ay2 - ay1 + 1.f;
  float acx = ax1 + 0.5f * aw;
  float acy = ay1 + 0.5f * ah;
  float cx = d0 * aw + acx;
  float cy = d1 * ah + acy;
  float pw = expf(d2) * aw;
  float ph = expf(d3) * ah;
  x1 = cx - 0.5f * pw;
  y1 = cy - 0.5f * ph;
  x2 = cx + 0.5f * pw;
  y2 = cy + 0.5f * ph;
  x1 = fminf(fmaxf(x1, 0.f), 1023.f);
  y1 = fminf(fmaxf(y1, 0.f), 1023.f);
  x2 = fminf(fmaxf(x2, 0.f), 1023.f);
  y2 = fminf(fmaxf(y2, 0.f), 1023.f);
}

__device__ __forceinline__ uint32_t f2ord(float f) {
  uint32_t u = __float_as_uint(f);
  return (u & 0x80000000u) ? ~u : (u | 0x80000000u);
}
__device__ __forceinline__ float ord2f(uint32_t u) {
  return (u & 0x80000000u) ? __uint_as_float(u ^ 0x80000000u) : __uint_as_float(~u);
}

// Kernel 1: masked ordered score keys, coalesced linear write keys[t]
__global__ void k_score(const float* __restrict__ labels, const float* __restrict__ bbox,
                        uint32_t* __restrict__ keys) {
  int t = blockIdx.x * 256 + threadIdx.x;
  if (t >= TOTAL) return;
  int pos = t & (HW - 1);
  int ba  = t >> 12;
  int a = ba % 9, b = ba / 9;
  float score = labels[((b * 18 + 2 * a + 1) << 12) + pos];
  const float* dp = bbox + ((b * 36 + 4 * a) << 12) + pos;
  float d0 = dp[0], d1 = dp[4096], d2 = dp[8192], d3 = dp[12288];
  int y = pos >> 6, x = pos & 63;
  float x1, y1, x2, y2;
  decode_box(a, x, y, d0, d1, d2, d3, x1, y1, x2, y2);
  bool keep = (x2 - x1 + 1.f >= 16.f) && (y2 - y1 + 1.f >= 16.f);
  float s = keep ? score : -INFINITY;
  keys[t] = f2ord(s);
}

// Kernel 2: per-batch LDS histogram + suffix scan for top-2000 threshold bin
// + compaction. 16 blocks x 1024. Global reads vectorized uint4.
__global__ __launch_bounds__(1024) void k_batch(const uint32_t* __restrict__ keys,
                                                ull* __restrict__ selKeys,
                                                uint32_t* __restrict__ counters) {
  int b = blockIdx.x, tid = threadIdx.x;
  int wave = tid >> 6, lane = tid & 63;
  __shared__ uint32_t hist[HBINS];         // 32 KB
  __shared__ uint32_t wtot[16];
  __shared__ uint32_t sh_T, sh_cnt;
  const uint32_t* kb = keys + b * NANCH;
  const uint4* kb4 = (const uint4*)kb;
#pragma unroll
  for (int k = 0; k < HBINS / 1024; ++k) hist[k * 1024 + tid] = 0u;
  if (tid == 0) { sh_T = 0u; sh_cnt = 0u; }
  __syncthreads();
  for (int i4 = tid; i4 < NANCH / 4; i4 += 1024) {
    uint4 v = kb4[i4];
    if (v.x & 0x80000000u) atomicAdd(&hist[v.x >> (32 - HBITS)], 1u);
    if (v.y & 0x80000000u) atomicAdd(&hist[v.y >> (32 - HBITS)], 1u);
    if (v.z & 0x80000000u) atomicAdd(&hist[v.z >> (32 - HBITS)], 1u);
    if (v.w & 0x80000000u) atomicAdd(&hist[v.w >> (32 - HBITS)], 1u);
  }
  __syncthreads();
  uint32_t c[8], suf[8];
#pragma unroll
  for (int k = 0; k < 8; ++k) c[k] = hist[tid * 8 + k];
  suf[7] = c[7];
#pragma unroll
  for (int k = 6; k >= 0; --k) suf[k] = c[k] + suf[k + 1];
  uint32_t total = suf[0];
  uint32_t wsuf = total;
#pragma unroll
  for (int off = 1; off < 64; off <<= 1) {
    uint32_t v = __shfl_down(wsuf, off);
    if (lane + off < 64) wsuf += v;
  }
  if (lane == 0) wtot[wave] = wsuf;
  __syncthreads();
  uint32_t wab = 0;
  for (int w = wave + 1; w < 16; ++w) wab += wtot[w];
  uint32_t ssum = wsuf + wab;          // keys in bins >= 8*tid
  uint32_t above_t = ssum - total;     // keys in bins >= 8*(tid+1)
  if (above_t < TOPN && ssum >= TOPN) {
    uint32_t T = (uint32_t)(tid * 8);
#pragma unroll
    for (int k = 7; k >= 0; --k) {
      uint32_t ab = above_t + ((k < 7) ? suf[k + 1] : 0u);
      if (ab < TOPN && ab + c[k] >= TOPN) T = (uint32_t)(tid * 8 + k);
    }
    sh_T = T;
  }
  __syncthreads();
  uint32_t T = sh_T;
  for (int i4 = tid; i4 < NANCH / 4; i4 += 1024) {
    uint4 v = kb4[i4];
    uint32_t vv[4] = { v.x, v.y, v.z, v.w };
#pragma unroll
    for (int cc = 0; cc < 4; ++cc) {
      uint32_t u = vv[cc];
      if ((u >> (32 - HBITS)) >= T) {
        uint32_t slot = atomicAdd(&sh_cnt, 1u);
        if (slot < SELPAD) {
          int i = i4 * 4 + cc;
          uint32_t canon = (uint32_t)((i & 4095) * 9 + (i >> 12));  // pos*9 + a
          selKeys[b * SELPAD + slot] = (((ull)(~u)) << 32) | canon;
        }
      }
    }
  }
  __syncthreads();
  if (tid == 0) counters[b] = (sh_cnt < SELPAD) ? sh_cnt : SELPAD;
}

// Kernel 3: rank-by-counting + decode + scatter of box/area/score to rank.
__global__ __launch_bounds__(256) void k_rank(const ull* __restrict__ selKeys,
                        const uint32_t* __restrict__ counters, const float* __restrict__ bbox,
                        float4* __restrict__ boxes, float* __restrict__ areas,
                        float* __restrict__ selScore) {
  int b = blockIdx.y;
  int i = blockIdx.x * 256 + threadIdx.x;
  int tid = threadIdx.x;
  uint32_t n = counters[b];
  const ull* sk = selKeys + b * SELPAD;
  ull ki = (i < (int)n) ? sk[i] : ~0ull;
  int rank = 0;
  __shared__ ull chunk[256];
  for (uint32_t base = 0; base < n; base += 256) {
    uint32_t j = base + (uint32_t)tid;
    chunk[tid] = (j < n) ? sk[j] : ~0ull;
    __syncthreads();
    int lim = (int)(n - base < 256u ? n - base : 256u);
    for (int t2 = 0; t2 < lim; ++t2) rank += (chunk[t2] < ki) ? 1 : 0;
    __syncthreads();
  }
  if (i < (int)n && rank < TOPN) {
    uint32_t idx = (uint32_t)ki;
    selScore[b * TOPN + rank] = ord2f(~((uint32_t)(ki >> 32)));
    int pos = (int)idx / 9, a = (int)idx - 9 * pos;
    int y = pos >> 6, x = pos & 63;
    const float* dp = bbox + ((b * 36 + 4 * a) << 12) + pos;
    float d0 = dp[0], d1 = dp[4096], d2 = dp[8192], d3 = dp[12288];
    float x1, y1, x2, y2;
    decode_box(a, x, y, d0, d1, d2, d3, x1, y1, x2, y2);
    boxes[b * PADN + rank] = make_float4(x1, y1, x2, y2);
    areas[b * PADN + rank] = (x2 - x1 + 1.f) * (y2 - y1 + 1.f);
  }
}

// Kernel 4: suppression mask build, 192 balanced blocks: grid (12 row-blocks,
// 16 batches) x 256 thr. Block owns 32 consecutive rows (never straddles a
// 64-boundary, so all rows share smin = rbase>>6) and writes exactly words
// s in [smin, 6) of each row — the words k_scan treats as valid. Lane owns
// column (s<<6)+lane with its box in registers (statically unrolled s);
// one __ballot builds each 64-bit word.
__global__ __launch_bounds__(256) void k_mask(const float4* __restrict__ boxes,
                                              const float* __restrict__ areas,
                                              ull* __restrict__ gmask) {
  int rb = blockIdx.x, b = blockIdx.y;
  int tid = threadIdx.x, wv = tid >> 6, lane = tid & 63;
  int rbase = rb * 32;
  int smin = rbase >> 6;
  __shared__ float4 sRow[32];
  __shared__ float  sAr[32];
  if (tid < 32) {
    sRow[tid] = boxes[b * PADN + rbase + tid];
    sAr[tid]  = areas[b * PADN + rbase + tid];
  }
  float4 bj[MSTRIPS];
  float  ja[MSTRIPS];
#pragma unroll
  for (int s = 0; s < MSTRIPS; ++s) {
    if (s >= smin) {
      bj[s] = boxes[b * PADN + (s << 6) + lane];
      ja[s] = areas[b * PADN + (s << 6) + lane];
    }
  }
  __syncthreads();
  const double MD = MIDC;
  for (int r = wv; r < 32; r += 4) {
    int i = rbase + r;
    float4 bi = sRow[r];
    float  ia = sAr[r];
#pragma unroll
    for (int s = 0; s < MSTRIPS; ++s) {
      if (s < smin) continue;
      int j = (s << 6) + lane;
      float iw = fminf(bi.z, bj[s].z) - fmaxf(bi.x, bj[s].x) + 1.f; iw = fmaxf(iw, 0.f);
      float ih = fminf(bi.w, bj[s].w) - fmaxf(bi.y, bj[s].y) + 1.f; ih = fmaxf(ih, 0.f);
      float inter = iw * ih;
      float uu = (ia + ja[s]) - inter;
      bool sup = (j > i) && ((double)inter >= MD * (double)uu);
      ull mb = __ballot(sup);
      if (lane == 0) gmask[((size_t)b * MNMS + i) * MPITCH + s] = mb;
    }
  }
}

// Kernel 5: single-wave greedy scan per batch over the global mask matrix
// (64B-aligned rows, L2-resident), 16-deep register prefetch, ballot bit
// test, exact early exit at 300 kept. Exact fallback (vs kept list) for
// candidates >= MNMS. Output: boxes f32[16][300][4] at 0, scores at 19200.
__global__ __launch_bounds__(64) void k_scan(const ull* __restrict__ gmask,
                                             const float4* __restrict__ boxes,
                                             const float* __restrict__ areas,
                                             const float* __restrict__ selScore,
                                             float* __restrict__ out) {
  int b = blockIdx.x, lane = threadIdx.x;   // 64 threads = 1 wave
  const ull* mb = gmask + (size_t)b * MNMS * MPITCH;
  int l8 = lane & 7;
  __shared__ int kidx[OUTN];
  __shared__ int sh_cnt;
  const double MD = MIDC;
  ull supw = 0ull;
  int cnt = 0;
  ull pf[GD2];
#pragma unroll
  for (int ph = 0; ph < GD2; ++ph) pf[ph] = mb[ph * MPITCH + l8];
  for (int base = 0; base < MNMS && cnt < OUTN; base += GD2) {
#pragma unroll
    for (int ph = 0; ph < GD2; ++ph) {
      int i = base + ph;
      ull bal = __ballot(((supw >> (i & 63)) & 1ull) != 0ull);
      if (!((bal >> (i >> 6)) & 1ull)) {       // uniform (lane i>>6 owns word)
        ull mm = (l8 >= (i >> 6) && l8 < MSTRIPS) ? pf[ph] : 0ull;
        supw |= mm;
        if (lane == 0 && cnt < OUTN) kidx[cnt] = i;
        cnt++;
      }
      int nx = i + GD2; if (nx > MNMS - 1) nx = MNMS - 1;
      pf[ph] = mb[nx * MPITCH + l8];           // prefetch
    }
  }
  // exact fallback: candidates beyond the mask matrix (rare/never)
  for (int i = MNMS; i < TOPN && cnt < OUTN; ++i) {
    float4 bi = boxes[b * PADN + i];
    float ia = areas[b * PADN + i];
    bool sup = false;
    for (int cb = 0; cb < cnt; cb += 64) {
      int k = cb + lane;
      if (k < cnt) {
        int kj = kidx[k];
        float4 bk = boxes[b * PADN + kj];
        float ka = areas[b * PADN + kj];
        float iw = fminf(bi.z, bk.z) - fmaxf(bi.x, bk.x) + 1.f; iw = fmaxf(iw, 0.f);
        float ih = fminf(bi.w, bk.w) - fmaxf(bi.y, bk.y) + 1.f; ih = fmaxf(ih, 0.f);
        float inter = iw * ih;
        float uu = (ia + ka) - inter;
        sup = sup || ((double)inter >= MD * (double)uu);
      }
    }
    if (!__any(sup)) {
      if (lane == 0) kidx[cnt] = i;
      cnt++;
    }
  }
  if (lane == 0) sh_cnt = (cnt < OUTN) ? cnt : OUTN;
  __syncthreads();
  int c = sh_cnt;
  float4* ob = (float4*)out;
  for (int s2 = lane; s2 < OUTN; s2 += 64) {
    float4 bx = make_float4(0.f, 0.f, 0.f, 0.f);
    float sc = 0.f;
    if (s2 < c) {
      int i = kidx[s2];
      bx = boxes[b * PADN + i];
      sc = selScore[b * TOPN + i];
    }
    ob[b * OUTN + s2] = bx;
    out[NB * OUTN * 4 + b * OUTN + s2] = sc;
  }
}

extern "C" void kernel_launch(void* const* d_in, const int* in_sizes, int n_in,
                              void* d_out, int out_size, void* d_ws, size_t ws_size,
                              hipStream_t stream) {
  const float* labels = (const float*)d_in[0];  // (16, 18, 64, 64)
  const float* bbox   = (const float*)d_in[1];  // (16, 36, 64, 64)
  char* ws = (char*)d_ws;
  // workspace layout (bytes):
  uint32_t* keys    = (uint32_t*)(ws + 0);         // 589824*4    = 2,359,296
  ull* selKeys      = (ull*)(ws + 2359296);        // 16*3072*8   =   393,216
  float* selScore   = (float*)(ws + 2752512);      // 16*2000*4   =   128,000
  float* areas      = (float*)(ws + 2880512);      // 16*2048*4   =   131,072
  float4* boxes     = (float4*)(ws + 3011584);     // 16*2048*16  =   524,288
  uint32_t* counters= (uint32_t*)(ws + 3535872);   // 64
  ull* gmask        = (ull*)(ws + 3535936);        // 16*384*8*8  =   393,216
  float* out = (float*)d_out;

  hipLaunchKernelGGL(k_score, dim3((TOTAL + 255) / 256), dim3(256), 0, stream, labels, bbox, keys);
  hipLaunchKernelGGL(k_batch, dim3(NB), dim3(1024), 0, stream, keys, selKeys, counters);
  hipLaunchKernelGGL(k_rank,  dim3(SELPAD / 256, NB), dim3(256), 0, stream, selKeys, counters, bbox, boxes, areas, selScore);
  hipLaunchKernelGGL(k_mask,  dim3(MNMS / 32, NB), dim3(256), 0, stream, boxes, areas, gmask);
  hipLaunchKernelGGL(k_scan,  dim3(NB), dim3(64), 0, stream, gmask, boxes, areas, selScore, out);
}